// Round 1
// baseline (2641.976 us; speedup 1.0000x reference)
//
#include <hip/hip_runtime.h>
#include <math.h>

// Problem constants: B=4, N=32768, D=256, H=8, S=64, DH=32
#define TS_N 32768
#define TS_M 131072   // B*N

// ---------------------------------------------------------------------------
// K1: FX = x@W_fx + b_fx ; XM = x@W_x + b_x
// SGEMM M=131072, K=256. BM=64, BN=128, BK=32, 256 thr, 4x8 micro
// blockIdx.y: 0,1 -> W_fx cols 0/128 ; 2,3 -> W_x cols 0/128
// ---------------------------------------------------------------------------
__global__ __launch_bounds__(256) void k1_proj(
    const float* __restrict__ x,
    const float* __restrict__ Wfx, const float* __restrict__ bfx,
    const float* __restrict__ Wx,  const float* __restrict__ bx,
    float* __restrict__ FX, float* __restrict__ XM)
{
    __shared__ float As[32][68];    // [k][m], padded (272B rows, 16B aligned)
    __shared__ float Bs[32][128];   // [k][n]
    const int t    = threadIdx.x;
    const int row0 = blockIdx.x * 64;
    const int by   = blockIdx.y;
    const float* W  = (by < 2) ? Wfx : Wx;
    const float* bb = (by < 2) ? bfx : bx;
    float* OUT      = (by < 2) ? FX  : XM;
    const int n0 = (by & 1) * 128;

    const int tx = t & 15, ty = t >> 4;
    const int am = t >> 2, ak = (t & 3) * 4;   // A staging: row am, k = ak, ak+16
    const int bk = t >> 3, bn = (t & 7) * 16;  // B staging: k = bk, 16 cols

    float acc[4][8];
#pragma unroll
    for (int i = 0; i < 4; ++i)
#pragma unroll
        for (int j = 0; j < 8; ++j) acc[i][j] = 0.f;

    for (int kk = 0; kk < 256; kk += 32) {
        float4 a0 = *(const float4*)&x[(row0 + am) * 256 + kk + ak];
        float4 a1 = *(const float4*)&x[(row0 + am) * 256 + kk + ak + 16];
        float4 w0 = *(const float4*)&W[(kk + bk) * 256 + n0 + bn];
        float4 w1 = *(const float4*)&W[(kk + bk) * 256 + n0 + bn + 4];
        float4 w2 = *(const float4*)&W[(kk + bk) * 256 + n0 + bn + 8];
        float4 w3 = *(const float4*)&W[(kk + bk) * 256 + n0 + bn + 12];
        __syncthreads();
        As[ak + 0][am] = a0.x; As[ak + 1][am] = a0.y; As[ak + 2][am] = a0.z; As[ak + 3][am] = a0.w;
        As[ak +16][am] = a1.x; As[ak +17][am] = a1.y; As[ak +18][am] = a1.z; As[ak +19][am] = a1.w;
        *(float4*)&Bs[bk][bn +  0] = w0;
        *(float4*)&Bs[bk][bn +  4] = w1;
        *(float4*)&Bs[bk][bn +  8] = w2;
        *(float4*)&Bs[bk][bn + 12] = w3;
        __syncthreads();
#pragma unroll 8
        for (int k = 0; k < 32; ++k) {
            float4 av = *(const float4*)&As[k][ty * 4];
            float4 b0 = *(const float4*)&Bs[k][tx * 4];
            float4 b1 = *(const float4*)&Bs[k][64 + tx * 4];
            float a_[4] = {av.x, av.y, av.z, av.w};
            float b_[8] = {b0.x, b0.y, b0.z, b0.w, b1.x, b1.y, b1.z, b1.w};
#pragma unroll
            for (int i = 0; i < 4; ++i)
#pragma unroll
                for (int j = 0; j < 8; ++j)
                    acc[i][j] = fmaf(a_[i], b_[j], acc[i][j]);
        }
    }
#pragma unroll
    for (int i = 0; i < 4; ++i) {
        const int row = row0 + ty * 4 + i;
        float4 o0, o1;
        o0.x = acc[i][0] + bb[n0 + tx * 4 + 0];
        o0.y = acc[i][1] + bb[n0 + tx * 4 + 1];
        o0.z = acc[i][2] + bb[n0 + tx * 4 + 2];
        o0.w = acc[i][3] + bb[n0 + tx * 4 + 3];
        o1.x = acc[i][4] + bb[n0 + 64 + tx * 4 + 0];
        o1.y = acc[i][5] + bb[n0 + 64 + tx * 4 + 1];
        o1.z = acc[i][6] + bb[n0 + 64 + tx * 4 + 2];
        o1.w = acc[i][7] + bb[n0 + 64 + tx * 4 + 3];
        *(float4*)&OUT[row * 256 + n0 + tx * 4]      = o0;
        *(float4*)&OUT[row * 256 + n0 + 64 + tx * 4] = o1;
    }
}

// ---------------------------------------------------------------------------
// K1b: logits = XM_head @ W_slice + b_slice, /temp[h], softmax over S=64
// One block: 64 rows x one head. K=32. 4x4 micro. Writes SW [M][512].
// ---------------------------------------------------------------------------
__global__ __launch_bounds__(256) void k1b_slice_softmax(
    const float* __restrict__ XM, const float* __restrict__ Wsl,
    const float* __restrict__ bsl, const float* __restrict__ temp,
    float* __restrict__ SW)
{
    __shared__ float XMs[32][68];  // [c][m]
    __shared__ float Ws[32][68];   // [c][s]
    __shared__ float Ls[64][68];   // logits tile [row][s]
    const int t  = threadIdx.x;
    const int r0 = blockIdx.x * 64;
    const int h  = blockIdx.y;

    {
        const int m = t >> 2, cq = (t & 3) * 8;
        float4 v0 = *(const float4*)&XM[(r0 + m) * 256 + h * 32 + cq];
        float4 v1 = *(const float4*)&XM[(r0 + m) * 256 + h * 32 + cq + 4];
        XMs[cq + 0][m] = v0.x; XMs[cq + 1][m] = v0.y; XMs[cq + 2][m] = v0.z; XMs[cq + 3][m] = v0.w;
        XMs[cq + 4][m] = v1.x; XMs[cq + 5][m] = v1.y; XMs[cq + 6][m] = v1.z; XMs[cq + 7][m] = v1.w;
        const int wk = t >> 3, wn = (t & 7) * 8;
        float4 u0 = *(const float4*)&Wsl[wk * 64 + wn];
        float4 u1 = *(const float4*)&Wsl[wk * 64 + wn + 4];
        *(float4*)&Ws[wk][wn]     = u0;
        *(float4*)&Ws[wk][wn + 4] = u1;
    }
    __syncthreads();

    const int tx = t & 15, ty = t >> 4;
    float acc[4][4];
#pragma unroll
    for (int i = 0; i < 4; ++i)
#pragma unroll
        for (int j = 0; j < 4; ++j) acc[i][j] = 0.f;
#pragma unroll
    for (int c = 0; c < 32; ++c) {
        float4 av = *(const float4*)&XMs[c][ty * 4];
        float4 bv = *(const float4*)&Ws[c][tx * 4];
        float a_[4] = {av.x, av.y, av.z, av.w};
        float b_[4] = {bv.x, bv.y, bv.z, bv.w};
#pragma unroll
        for (int i = 0; i < 4; ++i)
#pragma unroll
            for (int j = 0; j < 4; ++j)
                acc[i][j] = fmaf(a_[i], b_[j], acc[i][j]);
    }
    const float invt = 1.0f / temp[h];
#pragma unroll
    for (int i = 0; i < 4; ++i)
#pragma unroll
        for (int j = 0; j < 4; ++j)
            Ls[ty * 4 + i][tx * 4 + j] = (acc[i][j] + bsl[tx * 4 + j]) * invt;
    __syncthreads();

    const int row = t >> 2, j4 = t & 3;
    float v[16];
    float mx = -1e30f;
#pragma unroll
    for (int i = 0; i < 16; ++i) { v[i] = Ls[row][j4 * 16 + i]; mx = fmaxf(mx, v[i]); }
    mx = fmaxf(mx, __shfl_xor(mx, 1));
    mx = fmaxf(mx, __shfl_xor(mx, 2));
    float sum = 0.f;
#pragma unroll
    for (int i = 0; i < 16; ++i) { v[i] = expf(v[i] - mx); sum += v[i]; }
    sum += __shfl_xor(sum, 1);
    sum += __shfl_xor(sum, 2);
    const float inv = 1.0f / sum;
#pragma unroll
    for (int q = 0; q < 4; ++q) {
        float4 ov;
        ov.x = v[q * 4 + 0] * inv; ov.y = v[q * 4 + 1] * inv;
        ov.z = v[q * 4 + 2] * inv; ov.w = v[q * 4 + 3] * inv;
        *(float4*)&SW[(size_t)(r0 + row) * 512 + h * 64 + j4 * 16 + q * 4] = ov;
    }
}

// ---------------------------------------------------------------------------
// K2: partial pooling per (bh, 1024-row chunk).
// ---------------------------------------------------------------------------
__global__ __launch_bounds__(256) void k2_pool(
    const float* __restrict__ FX, const float* __restrict__ SW,
    float* __restrict__ PART, float* __restrict__ PARTN)
{
    __shared__ float SWs[16][64];
    __shared__ float FXs[16][32];
    const int t = threadIdx.x;
    const int chunk = blockIdx.x;   // 0..31
    const int bh = blockIdx.y;      // 0..31
    const int b = bh >> 3, h = bh & 7;
    const int gbase = b * TS_N + chunk * 1024;
    const int c = t & 31, sb = (t >> 5) * 8;
    float acc[8];
#pragma unroll
    for (int j = 0; j < 8; ++j) acc[j] = 0.f;
    float accn = 0.f;

    for (int t0 = 0; t0 < 1024; t0 += 16) {
        {
            const int rr = t >> 4, s4 = (t & 15) * 4;
            *(float4*)&SWs[rr][s4] =
                *(const float4*)&SW[(size_t)(gbase + t0 + rr) * 512 + h * 64 + s4];
            if (t < 128) {
                const int r2 = t >> 3, c4 = (t & 7) * 4;
                *(float4*)&FXs[r2][c4] =
                    *(const float4*)&FX[(size_t)(gbase + t0 + r2) * 256 + h * 32 + c4];
            }
        }
        __syncthreads();
#pragma unroll
        for (int rr = 0; rr < 16; ++rr) {
            const float f = FXs[rr][c];
#pragma unroll
            for (int j = 0; j < 8; ++j)
                acc[j] = fmaf(f, SWs[rr][sb + j], acc[j]);
        }
        if (t < 64) {
#pragma unroll
            for (int rr = 0; rr < 16; ++rr) accn += SWs[rr][t];
        }
        __syncthreads();
    }
    const int pbase = (bh * 32 + chunk) * 2048;
#pragma unroll
    for (int j = 0; j < 8; ++j) PART[pbase + (sb + j) * 32 + c] = acc[j];
    if (t < 64) PARTN[(bh * 32 + chunk) * 64 + t] = accn;
}

// ---------------------------------------------------------------------------
// K2b: deterministic reduce of chunk partials.
// ---------------------------------------------------------------------------
__global__ __launch_bounds__(256) void k2b_reduce(
    const float* __restrict__ PART, const float* __restrict__ PARTN,
    float* __restrict__ ST, float* __restrict__ NORM)
{
    const int bh = blockIdx.x, t = threadIdx.x;
#pragma unroll
    for (int j = 0; j < 8; ++j) {
        const int e = j * 256 + t;
        float s = 0.f;
        for (int ch = 0; ch < 32; ++ch) s += PART[(bh * 32 + ch) * 2048 + e];
        ST[bh * 2048 + e] = s;
    }
    if (t < 64) {
        float s = 0.f;
        for (int ch = 0; ch < 32; ++ch) s += PARTN[(bh * 32 + ch) * 64 + t];
        NORM[bh * 64 + t] = s;
    }
}

// ---------------------------------------------------------------------------
// K3: tiny attention among 64 slice tokens per (b,h). 1 wave per block.
// ---------------------------------------------------------------------------
__global__ __launch_bounds__(64) void k3_attn(
    const float* __restrict__ ST, const float* __restrict__ NORM,
    const float* __restrict__ Wqkv, float* __restrict__ OST)
{
    __shared__ float Wq[32 * 96];
    __shared__ float Kl[64][32];
    __shared__ float Vl[64][32];
    __shared__ float Dl[64][68];
    const int bh = blockIdx.x;
    const int s  = threadIdx.x;

    for (int i = 0; i < 48; ++i) Wq[i * 64 + s] = Wqkv[i * 64 + s];
    float st[32];
    const float nrm = NORM[bh * 64 + s] + 1e-5f;
#pragma unroll
    for (int c = 0; c < 32; ++c) st[c] = ST[bh * 2048 + s * 32 + c] / nrm;
    __syncthreads();

    float q[32];
#pragma unroll
    for (int o4 = 0; o4 < 8; ++o4) {
        float ax = 0.f, ay = 0.f, az = 0.f, aw = 0.f;
#pragma unroll
        for (int c = 0; c < 32; ++c) {
            float4 w = *(const float4*)&Wq[c * 96 + o4 * 4];
            ax = fmaf(st[c], w.x, ax); ay = fmaf(st[c], w.y, ay);
            az = fmaf(st[c], w.z, az); aw = fmaf(st[c], w.w, aw);
        }
        q[o4 * 4 + 0] = ax; q[o4 * 4 + 1] = ay; q[o4 * 4 + 2] = az; q[o4 * 4 + 3] = aw;
    }
#pragma unroll
    for (int o4 = 0; o4 < 8; ++o4) {
        float ax = 0.f, ay = 0.f, az = 0.f, aw = 0.f;
#pragma unroll
        for (int c = 0; c < 32; ++c) {
            float4 w = *(const float4*)&Wq[c * 96 + 32 + o4 * 4];
            ax = fmaf(st[c], w.x, ax); ay = fmaf(st[c], w.y, ay);
            az = fmaf(st[c], w.z, az); aw = fmaf(st[c], w.w, aw);
        }
        float4 kv; kv.x = ax; kv.y = ay; kv.z = az; kv.w = aw;
        *(float4*)&Kl[s][o4 * 4] = kv;
    }
#pragma unroll
    for (int o4 = 0; o4 < 8; ++o4) {
        float ax = 0.f, ay = 0.f, az = 0.f, aw = 0.f;
#pragma unroll
        for (int c = 0; c < 32; ++c) {
            float4 w = *(const float4*)&Wq[c * 96 + 64 + o4 * 4];
            ax = fmaf(st[c], w.x, ax); ay = fmaf(st[c], w.y, ay);
            az = fmaf(st[c], w.z, az); aw = fmaf(st[c], w.w, aw);
        }
        float4 vv; vv.x = ax; vv.y = ay; vv.z = az; vv.w = aw;
        *(float4*)&Vl[s][o4 * 4] = vv;
    }
    __syncthreads();

    const float scale = 0.17677669529663687f;  // 32^-0.5
    float mx = -1e30f;
    for (int t2 = 0; t2 < 64; ++t2) {
        float d = 0.f;
#pragma unroll
        for (int c4 = 0; c4 < 8; ++c4) {
            float4 kv = *(const float4*)&Kl[t2][c4 * 4];
            d = fmaf(q[c4 * 4 + 0], kv.x, d); d = fmaf(q[c4 * 4 + 1], kv.y, d);
            d = fmaf(q[c4 * 4 + 2], kv.z, d); d = fmaf(q[c4 * 4 + 3], kv.w, d);
        }
        d *= scale;
        Dl[s][t2] = d;
        mx = fmaxf(mx, d);
    }
    float sum = 0.f;
    for (int t2 = 0; t2 < 64; ++t2) { float e = expf(Dl[s][t2] - mx); Dl[s][t2] = e; sum += e; }
    const float inv = 1.0f / sum;
    float out[32];
#pragma unroll
    for (int c = 0; c < 32; ++c) out[c] = 0.f;
    for (int t2 = 0; t2 < 64; ++t2) {
        const float p = Dl[s][t2] * inv;
#pragma unroll
        for (int c4 = 0; c4 < 8; ++c4) {
            float4 vv = *(const float4*)&Vl[t2][c4 * 4];
            out[c4 * 4 + 0] = fmaf(p, vv.x, out[c4 * 4 + 0]);
            out[c4 * 4 + 1] = fmaf(p, vv.y, out[c4 * 4 + 1]);
            out[c4 * 4 + 2] = fmaf(p, vv.z, out[c4 * 4 + 2]);
            out[c4 * 4 + 3] = fmaf(p, vv.w, out[c4 * 4 + 3]);
        }
    }
#pragma unroll
    for (int c4 = 0; c4 < 8; ++c4) {
        float4 ov;
        ov.x = out[c4 * 4 + 0]; ov.y = out[c4 * 4 + 1];
        ov.z = out[c4 * 4 + 2]; ov.w = out[c4 * 4 + 3];
        *(float4*)&OST[bh * 2048 + s * 32 + c4 * 4] = ov;
    }
}

// ---------------------------------------------------------------------------
// K4: fused scatter (out_x) + final GEMM with W_out. out_x only in LDS.
// ---------------------------------------------------------------------------
__global__ __launch_bounds__(256) void k4_scatter_out(
    const float* __restrict__ SW, const float* __restrict__ OST,
    const float* __restrict__ Wout, const float* __restrict__ bout,
    float* __restrict__ out)
{
    __shared__ float SWs[16][512];
    __shared__ float OXs[16][260];
    const int t  = threadIdx.x;
    const int r0 = blockIdx.x * 16;
    const int b  = r0 >> 15;

    {
        const int rr = t >> 4, c0 = (t & 15) * 4;
#pragma unroll
        for (int j = 0; j < 8; ++j)
            *(float4*)&SWs[rr][c0 + j * 64] =
                *(const float4*)&SW[(size_t)(r0 + rr) * 512 + c0 + j * 64];
    }
    __syncthreads();

    {   // phase A: scatter
        const int d = t, h = t >> 5, c = t & 31;
        const float* op = &OST[(b * 8 + h) * 2048 + c];
        float acc[16];
#pragma unroll
        for (int r = 0; r < 16; ++r) acc[r] = 0.f;
#pragma unroll 4
        for (int s = 0; s < 64; ++s) {
            const float w = op[s * 32];
#pragma unroll
            for (int r = 0; r < 16; ++r)
                acc[r] = fmaf(w, SWs[r][h * 64 + s], acc[r]);
        }
#pragma unroll
        for (int r = 0; r < 16; ++r) OXs[r][d] = acc[r];
    }
    __syncthreads();

    {   // phase B: final GEMM
        const int r = t >> 4, cg = t & 15;
        float acc[16];
#pragma unroll
        for (int j = 0; j < 16; ++j) acc[j] = bout[cg * 16 + j];
#pragma unroll 2
        for (int k = 0; k < 256; ++k) {
            const float ox = OXs[r][k];
            float4 w0 = *(const float4*)&Wout[k * 256 + cg * 16];
            float4 w1 = *(const float4*)&Wout[k * 256 + cg * 16 + 4];
            float4 w2 = *(const float4*)&Wout[k * 256 + cg * 16 + 8];
            float4 w3 = *(const float4*)&Wout[k * 256 + cg * 16 + 12];
            acc[0]  = fmaf(ox, w0.x, acc[0]);  acc[1]  = fmaf(ox, w0.y, acc[1]);
            acc[2]  = fmaf(ox, w0.z, acc[2]);  acc[3]  = fmaf(ox, w0.w, acc[3]);
            acc[4]  = fmaf(ox, w1.x, acc[4]);  acc[5]  = fmaf(ox, w1.y, acc[5]);
            acc[6]  = fmaf(ox, w1.z, acc[6]);  acc[7]  = fmaf(ox, w1.w, acc[7]);
            acc[8]  = fmaf(ox, w2.x, acc[8]);  acc[9]  = fmaf(ox, w2.y, acc[9]);
            acc[10] = fmaf(ox, w2.z, acc[10]); acc[11] = fmaf(ox, w2.w, acc[11]);
            acc[12] = fmaf(ox, w3.x, acc[12]); acc[13] = fmaf(ox, w3.y, acc[13]);
            acc[14] = fmaf(ox, w3.z, acc[14]); acc[15] = fmaf(ox, w3.w, acc[15]);
        }
#pragma unroll
        for (int j4 = 0; j4 < 4; ++j4) {
            float4 ov;
            ov.x = acc[j4 * 4 + 0]; ov.y = acc[j4 * 4 + 1];
            ov.z = acc[j4 * 4 + 2]; ov.w = acc[j4 * 4 + 3];
            *(float4*)&out[(size_t)(r0 + r) * 256 + cg * 16 + j4 * 4] = ov;
        }
    }
}

extern "C" void kernel_launch(void* const* d_in, const int* in_sizes, int n_in,
                              void* d_out, int out_size, void* d_ws, size_t ws_size,
                              hipStream_t stream) {
    (void)in_sizes; (void)n_in; (void)out_size; (void)ws_size;
    const float* x    = (const float*)d_in[0];
    const float* Wfx  = (const float*)d_in[1];
    const float* bfx  = (const float*)d_in[2];
    const float* Wx   = (const float*)d_in[3];
    const float* bx   = (const float*)d_in[4];
    const float* Wsl  = (const float*)d_in[5];
    const float* bsl  = (const float*)d_in[6];
    const float* temp = (const float*)d_in[7];
    const float* Wqkv = (const float*)d_in[8];
    const float* Wout = (const float*)d_in[9];
    const float* bout = (const float*)d_in[10];
    float* out = (float*)d_out;
    float* ws  = (float*)d_ws;

    float* XM    = ws;                   // 33,554,432 floats
    float* SW    = XM + 33554432;        // 67,108,864 floats
    float* PART  = SW + 67108864;        // 2,097,152 floats
    float* PARTN = PART + 2097152;       // 65,536 floats
    float* ST    = PARTN + 65536;        // 65,536 floats
    float* NORM  = ST + 65536;           // 2,048 floats
    float* OST   = NORM + 2048;          // 65,536 floats
    float* FX    = out;                  // d_out doubles as FX scratch

    k1_proj<<<dim3(TS_M / 64, 4), 256, 0, stream>>>(x, Wfx, bfx, Wx, bx, FX, XM);
    k1b_slice_softmax<<<dim3(TS_M / 64, 8), 256, 0, stream>>>(XM, Wsl, bsl, temp, SW);
    k2_pool<<<dim3(32, 32), 256, 0, stream>>>(FX, SW, PART, PARTN);
    k2b_reduce<<<32, 256, 0, stream>>>(PART, PARTN, ST, NORM);
    k3_attn<<<32, 64, 0, stream>>>(ST, NORM, Wqkv, OST);
    k4_scatter_out<<<8192, 256, 0, stream>>>(SW, OST, Wout, bout, out);
}

// Round 3
// 1222.646 us; speedup vs baseline: 2.1609x; 2.1609x over previous
//
#include <hip/hip_runtime.h>
#include <math.h>

// Problem constants: B=4, N=32768, D=256, H=8, S=64, DH=32
#define TS_N 32768
#define TS_M 131072   // B*N

// ---------------------------------------------------------------------------
// K1: FX = x@W_fx + b_fx ; XM = x@W_x + b_x
// SGEMM M=131072, K=256. BM=64, BN=128, BK=32, 256 thr, 4x8 micro
// blockIdx.y: 0,1 -> W_fx cols 0/128 ; 2,3 -> W_x cols 0/128
// ---------------------------------------------------------------------------
__global__ __launch_bounds__(256) void k1_proj(
    const float* __restrict__ x,
    const float* __restrict__ Wfx, const float* __restrict__ bfx,
    const float* __restrict__ Wx,  const float* __restrict__ bx,
    float* __restrict__ FX, float* __restrict__ XM)
{
    __shared__ float As[32][68];    // [k][m], padded
    __shared__ float Bs[32][128];   // [k][n]
    const int t    = threadIdx.x;
    const int row0 = blockIdx.x * 64;
    const int by   = blockIdx.y;
    const float* W  = (by < 2) ? Wfx : Wx;
    const float* bb = (by < 2) ? bfx : bx;
    float* OUT      = (by < 2) ? FX  : XM;
    const int n0 = (by & 1) * 128;

    const int tx = t & 15, ty = t >> 4;
    const int am = t >> 2, ak = (t & 3) * 4;
    const int bk = t >> 3, bn = (t & 7) * 16;

    float acc[4][8];
#pragma unroll
    for (int i = 0; i < 4; ++i)
#pragma unroll
        for (int j = 0; j < 8; ++j) acc[i][j] = 0.f;

    for (int kk = 0; kk < 256; kk += 32) {
        float4 a0 = *(const float4*)&x[(row0 + am) * 256 + kk + ak];
        float4 a1 = *(const float4*)&x[(row0 + am) * 256 + kk + ak + 16];
        float4 w0 = *(const float4*)&W[(kk + bk) * 256 + n0 + bn];
        float4 w1 = *(const float4*)&W[(kk + bk) * 256 + n0 + bn + 4];
        float4 w2 = *(const float4*)&W[(kk + bk) * 256 + n0 + bn + 8];
        float4 w3 = *(const float4*)&W[(kk + bk) * 256 + n0 + bn + 12];
        __syncthreads();
        As[ak + 0][am] = a0.x; As[ak + 1][am] = a0.y; As[ak + 2][am] = a0.z; As[ak + 3][am] = a0.w;
        As[ak +16][am] = a1.x; As[ak +17][am] = a1.y; As[ak +18][am] = a1.z; As[ak +19][am] = a1.w;
        *(float4*)&Bs[bk][bn +  0] = w0;
        *(float4*)&Bs[bk][bn +  4] = w1;
        *(float4*)&Bs[bk][bn +  8] = w2;
        *(float4*)&Bs[bk][bn + 12] = w3;
        __syncthreads();
#pragma unroll 8
        for (int k = 0; k < 32; ++k) {
            float4 av = *(const float4*)&As[k][ty * 4];
            float4 b0 = *(const float4*)&Bs[k][tx * 4];
            float4 b1 = *(const float4*)&Bs[k][64 + tx * 4];
            float a_[4] = {av.x, av.y, av.z, av.w};
            float b_[8] = {b0.x, b0.y, b0.z, b0.w, b1.x, b1.y, b1.z, b1.w};
#pragma unroll
            for (int i = 0; i < 4; ++i)
#pragma unroll
                for (int j = 0; j < 8; ++j)
                    acc[i][j] = fmaf(a_[i], b_[j], acc[i][j]);
        }
    }
#pragma unroll
    for (int i = 0; i < 4; ++i) {
        const int row = row0 + ty * 4 + i;
        float4 o0, o1;
        o0.x = acc[i][0] + bb[n0 + tx * 4 + 0];
        o0.y = acc[i][1] + bb[n0 + tx * 4 + 1];
        o0.z = acc[i][2] + bb[n0 + tx * 4 + 2];
        o0.w = acc[i][3] + bb[n0 + tx * 4 + 3];
        o1.x = acc[i][4] + bb[n0 + 64 + tx * 4 + 0];
        o1.y = acc[i][5] + bb[n0 + 64 + tx * 4 + 1];
        o1.z = acc[i][6] + bb[n0 + 64 + tx * 4 + 2];
        o1.w = acc[i][7] + bb[n0 + 64 + tx * 4 + 3];
        *(float4*)&OUT[row * 256 + n0 + tx * 4]      = o0;
        *(float4*)&OUT[row * 256 + n0 + 64 + tx * 4] = o1;
    }
}

// ---------------------------------------------------------------------------
// K1b: logits = XM_head @ W_slice + b_slice, /temp[h], softmax over S=64
// ---------------------------------------------------------------------------
__global__ __launch_bounds__(256) void k1b_slice_softmax(
    const float* __restrict__ XM, const float* __restrict__ Wsl,
    const float* __restrict__ bsl, const float* __restrict__ temp,
    float* __restrict__ SW)
{
    __shared__ float XMs[32][68];  // [c][m]
    __shared__ float Ws[32][68];   // [c][s]
    __shared__ float Ls[64][68];   // logits tile [row][s]
    const int t  = threadIdx.x;
    const int r0 = blockIdx.x * 64;
    const int h  = blockIdx.y;

    {
        const int m = t >> 2, cq = (t & 3) * 8;
        float4 v0 = *(const float4*)&XM[(r0 + m) * 256 + h * 32 + cq];
        float4 v1 = *(const float4*)&XM[(r0 + m) * 256 + h * 32 + cq + 4];
        XMs[cq + 0][m] = v0.x; XMs[cq + 1][m] = v0.y; XMs[cq + 2][m] = v0.z; XMs[cq + 3][m] = v0.w;
        XMs[cq + 4][m] = v1.x; XMs[cq + 5][m] = v1.y; XMs[cq + 6][m] = v1.z; XMs[cq + 7][m] = v1.w;
        const int wk = t >> 3, wn = (t & 7) * 8;
        float4 u0 = *(const float4*)&Wsl[wk * 64 + wn];
        float4 u1 = *(const float4*)&Wsl[wk * 64 + wn + 4];
        *(float4*)&Ws[wk][wn]     = u0;
        *(float4*)&Ws[wk][wn + 4] = u1;
    }
    __syncthreads();

    const int tx = t & 15, ty = t >> 4;
    float acc[4][4];
#pragma unroll
    for (int i = 0; i < 4; ++i)
#pragma unroll
        for (int j = 0; j < 4; ++j) acc[i][j] = 0.f;
#pragma unroll
    for (int c = 0; c < 32; ++c) {
        float4 av = *(const float4*)&XMs[c][ty * 4];
        float4 bv = *(const float4*)&Ws[c][tx * 4];
        float a_[4] = {av.x, av.y, av.z, av.w};
        float b_[4] = {bv.x, bv.y, bv.z, bv.w};
#pragma unroll
        for (int i = 0; i < 4; ++i)
#pragma unroll
            for (int j = 0; j < 4; ++j)
                acc[i][j] = fmaf(a_[i], b_[j], acc[i][j]);
    }
    const float invt = 1.0f / temp[h];
#pragma unroll
    for (int i = 0; i < 4; ++i)
#pragma unroll
        for (int j = 0; j < 4; ++j)
            Ls[ty * 4 + i][tx * 4 + j] = (acc[i][j] + bsl[tx * 4 + j]) * invt;
    __syncthreads();

    const int row = t >> 2, j4 = t & 3;
    float v[16];
    float mx = -1e30f;
#pragma unroll
    for (int i = 0; i < 16; ++i) { v[i] = Ls[row][j4 * 16 + i]; mx = fmaxf(mx, v[i]); }
    mx = fmaxf(mx, __shfl_xor(mx, 1));
    mx = fmaxf(mx, __shfl_xor(mx, 2));
    float sum = 0.f;
#pragma unroll
    for (int i = 0; i < 16; ++i) { v[i] = expf(v[i] - mx); sum += v[i]; }
    sum += __shfl_xor(sum, 1);
    sum += __shfl_xor(sum, 2);
    const float inv = 1.0f / sum;
#pragma unroll
    for (int q = 0; q < 4; ++q) {
        float4 ov;
        ov.x = v[q * 4 + 0] * inv; ov.y = v[q * 4 + 1] * inv;
        ov.z = v[q * 4 + 2] * inv; ov.w = v[q * 4 + 3] * inv;
        *(float4*)&SW[(size_t)(r0 + row) * 512 + h * 64 + j4 * 16 + q * 4] = ov;
    }
}

// ---------------------------------------------------------------------------
// K2: partial pooling per (bh, 1024-row chunk).
// ---------------------------------------------------------------------------
__global__ __launch_bounds__(256) void k2_pool(
    const float* __restrict__ FX, const float* __restrict__ SW,
    float* __restrict__ PART, float* __restrict__ PARTN)
{
    __shared__ float SWs[16][64];
    __shared__ float FXs[16][32];
    const int t = threadIdx.x;
    const int chunk = blockIdx.x;   // 0..31
    const int bh = blockIdx.y;      // 0..31
    const int b = bh >> 3, h = bh & 7;
    const int gbase = b * TS_N + chunk * 1024;
    const int c = t & 31, sb = (t >> 5) * 8;
    float acc[8];
#pragma unroll
    for (int j = 0; j < 8; ++j) acc[j] = 0.f;
    float accn = 0.f;

    for (int t0 = 0; t0 < 1024; t0 += 16) {
        {
            const int rr = t >> 4, s4 = (t & 15) * 4;
            *(float4*)&SWs[rr][s4] =
                *(const float4*)&SW[(size_t)(gbase + t0 + rr) * 512 + h * 64 + s4];
            if (t < 128) {
                const int r2 = t >> 3, c4 = (t & 7) * 4;
                *(float4*)&FXs[r2][c4] =
                    *(const float4*)&FX[(size_t)(gbase + t0 + r2) * 256 + h * 32 + c4];
            }
        }
        __syncthreads();
#pragma unroll
        for (int rr = 0; rr < 16; ++rr) {
            const float f = FXs[rr][c];
#pragma unroll
            for (int j = 0; j < 8; ++j)
                acc[j] = fmaf(f, SWs[rr][sb + j], acc[j]);
        }
        if (t < 64) {
#pragma unroll
            for (int rr = 0; rr < 16; ++rr) accn += SWs[rr][t];
        }
        __syncthreads();
    }
    const int pbase = (bh * 32 + chunk) * 2048;
#pragma unroll
    for (int j = 0; j < 8; ++j) PART[pbase + (sb + j) * 32 + c] = acc[j];
    if (t < 64) PARTN[(bh * 32 + chunk) * 64 + t] = accn;
}

// ---------------------------------------------------------------------------
// K2b: deterministic reduce of chunk partials.
// ---------------------------------------------------------------------------
__global__ __launch_bounds__(256) void k2b_reduce(
    const float* __restrict__ PART, const float* __restrict__ PARTN,
    float* __restrict__ ST, float* __restrict__ NORM)
{
    const int bh = blockIdx.x, t = threadIdx.x;
#pragma unroll
    for (int j = 0; j < 8; ++j) {
        const int e = j * 256 + t;
        float s = 0.f;
        for (int ch = 0; ch < 32; ++ch) s += PART[(bh * 32 + ch) * 2048 + e];
        ST[bh * 2048 + e] = s;
    }
    if (t < 64) {
        float s = 0.f;
        for (int ch = 0; ch < 32; ++ch) s += PARTN[(bh * 32 + ch) * 64 + t];
        NORM[bh * 64 + t] = s;
    }
}

// ---------------------------------------------------------------------------
// K3: tiny attention among 64 slice tokens per (b,h). 1 wave per block.
// ---------------------------------------------------------------------------
__global__ __launch_bounds__(64) void k3_attn(
    const float* __restrict__ ST, const float* __restrict__ NORM,
    const float* __restrict__ Wqkv, float* __restrict__ OST)
{
    __shared__ float Wq[32 * 96];
    __shared__ float Kl[64][32];
    __shared__ float Vl[64][32];
    __shared__ float Dl[64][68];
    const int bh = blockIdx.x;
    const int s  = threadIdx.x;

    for (int i = 0; i < 48; ++i) Wq[i * 64 + s] = Wqkv[i * 64 + s];
    float st[32];
    const float nrm = NORM[bh * 64 + s] + 1e-5f;
#pragma unroll
    for (int c = 0; c < 32; ++c) st[c] = ST[bh * 2048 + s * 32 + c] / nrm;
    __syncthreads();

    float q[32];
#pragma unroll
    for (int o4 = 0; o4 < 8; ++o4) {
        float ax = 0.f, ay = 0.f, az = 0.f, aw = 0.f;
#pragma unroll
        for (int c = 0; c < 32; ++c) {
            float4 w = *(const float4*)&Wq[c * 96 + o4 * 4];
            ax = fmaf(st[c], w.x, ax); ay = fmaf(st[c], w.y, ay);
            az = fmaf(st[c], w.z, az); aw = fmaf(st[c], w.w, aw);
        }
        q[o4 * 4 + 0] = ax; q[o4 * 4 + 1] = ay; q[o4 * 4 + 2] = az; q[o4 * 4 + 3] = aw;
    }
#pragma unroll
    for (int o4 = 0; o4 < 8; ++o4) {
        float ax = 0.f, ay = 0.f, az = 0.f, aw = 0.f;
#pragma unroll
        for (int c = 0; c < 32; ++c) {
            float4 w = *(const float4*)&Wq[c * 96 + 32 + o4 * 4];
            ax = fmaf(st[c], w.x, ax); ay = fmaf(st[c], w.y, ay);
            az = fmaf(st[c], w.z, az); aw = fmaf(st[c], w.w, aw);
        }
        float4 kv; kv.x = ax; kv.y = ay; kv.z = az; kv.w = aw;
        *(float4*)&Kl[s][o4 * 4] = kv;
    }
#pragma unroll
    for (int o4 = 0; o4 < 8; ++o4) {
        float ax = 0.f, ay = 0.f, az = 0.f, aw = 0.f;
#pragma unroll
        for (int c = 0; c < 32; ++c) {
            float4 w = *(const float4*)&Wq[c * 96 + 64 + o4 * 4];
            ax = fmaf(st[c], w.x, ax); ay = fmaf(st[c], w.y, ay);
            az = fmaf(st[c], w.z, az); aw = fmaf(st[c], w.w, aw);
        }
        float4 vv; vv.x = ax; vv.y = ay; vv.z = az; vv.w = aw;
        *(float4*)&Vl[s][o4 * 4] = vv;
    }
    __syncthreads();

    const float scale = 0.17677669529663687f;  // 32^-0.5
    float mx = -1e30f;
    for (int t2 = 0; t2 < 64; ++t2) {
        float d = 0.f;
#pragma unroll
        for (int c4 = 0; c4 < 8; ++c4) {
            float4 kv = *(const float4*)&Kl[t2][c4 * 4];
            d = fmaf(q[c4 * 4 + 0], kv.x, d); d = fmaf(q[c4 * 4 + 1], kv.y, d);
            d = fmaf(q[c4 * 4 + 2], kv.z, d); d = fmaf(q[c4 * 4 + 3], kv.w, d);
        }
        d *= scale;
        Dl[s][t2] = d;
        mx = fmaxf(mx, d);
    }
    float sum = 0.f;
    for (int t2 = 0; t2 < 64; ++t2) { float e = expf(Dl[s][t2] - mx); Dl[s][t2] = e; sum += e; }
    const float inv = 1.0f / sum;
    float out[32];
#pragma unroll
    for (int c = 0; c < 32; ++c) out[c] = 0.f;
    for (int t2 = 0; t2 < 64; ++t2) {
        const float p = Dl[s][t2] * inv;
#pragma unroll
        for (int c4 = 0; c4 < 8; ++c4) {
            float4 vv = *(const float4*)&Vl[t2][c4 * 4];
            out[c4 * 4 + 0] = fmaf(p, vv.x, out[c4 * 4 + 0]);
            out[c4 * 4 + 1] = fmaf(p, vv.y, out[c4 * 4 + 1]);
            out[c4 * 4 + 2] = fmaf(p, vv.z, out[c4 * 4 + 2]);
            out[c4 * 4 + 3] = fmaf(p, vv.w, out[c4 * 4 + 3]);
        }
    }
#pragma unroll
    for (int c4 = 0; c4 < 8; ++c4) {
        float4 ov;
        ov.x = out[c4 * 4 + 0]; ov.y = out[c4 * 4 + 1];
        ov.z = out[c4 * 4 + 2]; ov.w = out[c4 * 4 + 3];
        *(float4*)&OST[bh * 2048 + s * 32 + c4 * 4] = ov;
    }
}

// ---------------------------------------------------------------------------
// K3b: precombine G[b, h*64+s, :] = OST[bh,s,:] @ Wout[h*32:(h+1)*32, :]
// One block per bh (32 blocks, 256 threads; thread t owns output col t).
// ---------------------------------------------------------------------------
__global__ __launch_bounds__(256) void k3b_precomb(
    const float* __restrict__ OST, const float* __restrict__ Wout,
    float* __restrict__ G)
{
    __shared__ float OSTs[64][36];   // [s][c], padded
    __shared__ float Wc[32][256];    // [c][o]
    const int bh = blockIdx.x;
    const int b = bh >> 3, h = bh & 7;
    const int t = threadIdx.x;

    // stage OST tile [64][32]
#pragma unroll
    for (int j = 0; j < 2; ++j) {
        const int e = (j * 256 + t) * 4;       // 0..2044, step 4
        float4 v = *(const float4*)&OST[bh * 2048 + e];
        const int s = e >> 5, c = e & 31;
        OSTs[s][c + 0] = v.x; OSTs[s][c + 1] = v.y;
        OSTs[s][c + 2] = v.z; OSTs[s][c + 3] = v.w;
    }
    // stage Wout head rows [32][256]
#pragma unroll
    for (int j = 0; j < 8; ++j) {
        const int e = (j * 256 + t) * 4;       // 0..8188
        const int c = e >> 8, o = e & 255;
        *(float4*)&Wc[c][o] = *(const float4*)&Wout[(h * 32 + c) * 256 + o];
    }
    __syncthreads();

    float wcol[32];
#pragma unroll
    for (int c = 0; c < 32; ++c) wcol[c] = Wc[c][t];

    for (int s = 0; s < 64; ++s) {
        float a = 0.f;
#pragma unroll
        for (int c = 0; c < 32; ++c) a = fmaf(OSTs[s][c], wcol[c], a);
        G[(size_t)(bh * 64 + s) * 256 + t] = a;
    }
}

// ---------------------------------------------------------------------------
// K4: out = SW[131072x512] @ G_b[512x256] + bout.  Same SGEMM structure as K1.
// BM=64, BN=128, BK=32, 256 thr, 4x8 micro. grid (2048, 2).
// ---------------------------------------------------------------------------
__global__ __launch_bounds__(256) void k4_gemm(
    const float* __restrict__ SW, const float* __restrict__ G,
    const float* __restrict__ bout, float* __restrict__ out)
{
    __shared__ float As[32][68];
    __shared__ float Bs[32][128];
    const int t    = threadIdx.x;
    const int row0 = blockIdx.x * 64;
    const int n0   = blockIdx.y * 128;
    const int b    = row0 >> 15;
    const float* Gb = G + (size_t)b * 512 * 256;

    const int tx = t & 15, ty = t >> 4;
    const int am = t >> 2, ak = (t & 3) * 4;
    const int bk = t >> 3, bn = (t & 7) * 16;

    float acc[4][8];
#pragma unroll
    for (int i = 0; i < 4; ++i)
#pragma unroll
        for (int j = 0; j < 8; ++j) acc[i][j] = 0.f;

    for (int kk = 0; kk < 512; kk += 32) {
        float4 a0 = *(const float4*)&SW[(size_t)(row0 + am) * 512 + kk + ak];
        float4 a1 = *(const float4*)&SW[(size_t)(row0 + am) * 512 + kk + ak + 16];
        float4 w0 = *(const float4*)&Gb[(kk + bk) * 256 + n0 + bn];
        float4 w1 = *(const float4*)&Gb[(kk + bk) * 256 + n0 + bn + 4];
        float4 w2 = *(const float4*)&Gb[(kk + bk) * 256 + n0 + bn + 8];
        float4 w3 = *(const float4*)&Gb[(kk + bk) * 256 + n0 + bn + 12];
        __syncthreads();
        As[ak + 0][am] = a0.x; As[ak + 1][am] = a0.y; As[ak + 2][am] = a0.z; As[ak + 3][am] = a0.w;
        As[ak +16][am] = a1.x; As[ak +17][am] = a1.y; As[ak +18][am] = a1.z; As[ak +19][am] = a1.w;
        *(float4*)&Bs[bk][bn +  0] = w0;
        *(float4*)&Bs[bk][bn +  4] = w1;
        *(float4*)&Bs[bk][bn +  8] = w2;
        *(float4*)&Bs[bk][bn + 12] = w3;
        __syncthreads();
#pragma unroll 8
        for (int k = 0; k < 32; ++k) {
            float4 av = *(const float4*)&As[k][ty * 4];
            float4 b0 = *(const float4*)&Bs[k][tx * 4];
            float4 b1 = *(const float4*)&Bs[k][64 + tx * 4];
            float a_[4] = {av.x, av.y, av.z, av.w};
            float b_[8] = {b0.x, b0.y, b0.z, b0.w, b1.x, b1.y, b1.z, b1.w};
#pragma unroll
            for (int i = 0; i < 4; ++i)
#pragma unroll
                for (int j = 0; j < 8; ++j)
                    acc[i][j] = fmaf(a_[i], b_[j], acc[i][j]);
        }
    }
#pragma unroll
    for (int i = 0; i < 4; ++i) {
        const int row = row0 + ty * 4 + i;
        float4 o0, o1;
        o0.x = acc[i][0] + bout[n0 + tx * 4 + 0];
        o0.y = acc[i][1] + bout[n0 + tx * 4 + 1];
        o0.z = acc[i][2] + bout[n0 + tx * 4 + 2];
        o0.w = acc[i][3] + bout[n0 + tx * 4 + 3];
        o1.x = acc[i][4] + bout[n0 + 64 + tx * 4 + 0];
        o1.y = acc[i][5] + bout[n0 + 64 + tx * 4 + 1];
        o1.z = acc[i][6] + bout[n0 + 64 + tx * 4 + 2];
        o1.w = acc[i][7] + bout[n0 + 64 + tx * 4 + 3];
        *(float4*)&out[(size_t)row * 256 + n0 + tx * 4]      = o0;
        *(float4*)&out[(size_t)row * 256 + n0 + 64 + tx * 4] = o1;
    }
}

extern "C" void kernel_launch(void* const* d_in, const int* in_sizes, int n_in,
                              void* d_out, int out_size, void* d_ws, size_t ws_size,
                              hipStream_t stream) {
    (void)in_sizes; (void)n_in; (void)out_size; (void)ws_size;
    const float* x    = (const float*)d_in[0];
    const float* Wfx  = (const float*)d_in[1];
    const float* bfx  = (const float*)d_in[2];
    const float* Wx   = (const float*)d_in[3];
    const float* bx   = (const float*)d_in[4];
    const float* Wsl  = (const float*)d_in[5];
    const float* bsl  = (const float*)d_in[6];
    const float* temp = (const float*)d_in[7];
    const float* Wqkv = (const float*)d_in[8];
    const float* Wout = (const float*)d_in[9];
    const float* bout = (const float*)d_in[10];
    float* out = (float*)d_out;
    float* ws  = (float*)d_ws;

    float* XM    = ws;                   // 33,554,432 floats
    float* SW    = XM + 33554432;        // 67,108,864 floats
    float* PART  = SW + 67108864;        // 2,097,152 floats
    float* PARTN = PART + 2097152;       // 65,536 floats
    float* ST    = PARTN + 65536;        // 65,536 floats
    float* NORM  = ST + 65536;           // 2,048 floats
    float* OST   = NORM + 2048;          // 65,536 floats
    float* G     = PART;                 // reuse PART region (free after k2b); 524,288 floats
    float* FX    = out;                  // d_out doubles as FX scratch (consumed by k2 before k4 writes)

    k1_proj<<<dim3(TS_M / 64, 4), 256, 0, stream>>>(x, Wfx, bfx, Wx, bx, FX, XM);
    k1b_slice_softmax<<<dim3(TS_M / 64, 8), 256, 0, stream>>>(XM, Wsl, bsl, temp, SW);
    k2_pool<<<dim3(32, 32), 256, 0, stream>>>(FX, SW, PART, PARTN);
    k2b_reduce<<<32, 256, 0, stream>>>(PART, PARTN, ST, NORM);
    k3_attn<<<32, 64, 0, stream>>>(ST, NORM, Wqkv, OST);
    k3b_precomb<<<32, 256, 0, stream>>>(OST, Wout, G);
    k4_gemm<<<dim3(TS_M / 64, 2), 256, 0, stream>>>(SW, G, bout, out);
}

// Round 4
// 848.590 us; speedup vs baseline: 3.1134x; 1.4408x over previous
//
#include <hip/hip_runtime.h>
#include <math.h>

// Problem constants: B=4, N=32768, D=256, H=8, S=64, DH=32
#define TS_N 32768
#define TS_M 131072   // B*N

typedef short bf16x8 __attribute__((ext_vector_type(8)));
typedef float f32x4  __attribute__((ext_vector_type(4)));
typedef unsigned short us4 __attribute__((ext_vector_type(4)));

static __device__ __forceinline__ unsigned short f2bf(float f) {
    unsigned u = __float_as_uint(f);
    u = u + 0x7FFF + ((u >> 16) & 1);   // RNE
    return (unsigned short)(u >> 16);
}
static __device__ __forceinline__ float bf2f(unsigned short b) {
    return __uint_as_float(((unsigned)b) << 16);
}

// ---------------------------------------------------------------------------
// K0: split x (f32) -> Xh, Xl (bf16 hi/lo), vectorized 4-wide
// ---------------------------------------------------------------------------
__global__ __launch_bounds__(256) void k0_split(
    const float* __restrict__ src, unsigned short* __restrict__ h,
    unsigned short* __restrict__ l, int n4)
{
    for (int i = blockIdx.x * 256 + threadIdx.x; i < n4; i += gridDim.x * 256) {
        float4 v = ((const float4*)src)[i];
        us4 vh, vl;
        float c[4] = {v.x, v.y, v.z, v.w};
#pragma unroll
        for (int j = 0; j < 4; ++j) {
            unsigned short hh = f2bf(c[j]);
            vh[j] = hh;
            vl[j] = f2bf(c[j] - bf2f(hh));
        }
        ((us4*)h)[i] = vh;
        ((us4*)l)[i] = vl;
    }
}

// ---------------------------------------------------------------------------
// K0w: convert + transpose Wfx, Wx -> Wt[w][n][k] bf16 hi/lo
// ---------------------------------------------------------------------------
__global__ __launch_bounds__(256) void k0_wt(
    const float* __restrict__ Wfx, const float* __restrict__ Wx,
    unsigned short* __restrict__ Wth, unsigned short* __restrict__ Wtl)
{
    const int n = blockIdx.x;       // 0..255 (output col of W = row of Wt)
    const int wsel = blockIdx.y;    // 0..1
    const int k = threadIdx.x;      // 0..255
    const float v = (wsel ? Wx : Wfx)[k * 256 + n];
    const unsigned short hh = f2bf(v);
    const int idx = (wsel * 256 + n) * 256 + k;
    Wth[idx] = hh;
    Wtl[idx] = f2bf(v - bf2f(hh));
}

// ---------------------------------------------------------------------------
// GEMM (split-bf16 MFMA): OUT[M][256] = (Ah+Al)[M][K] @ (Bh+Bl)^T[256][K] + bias
// B given TRANSPOSED: Bt[n][k]. BM=128, BN=128, BK=32, 256 thr = 4 waves,
// per-wave 64x64 via 4x4 frags of mfma_f32_16x16x32_bf16, 3 MFMAs per frag
// (hi*hi + hi*lo + lo*hi). Fragment-contiguous LDS: chunk(r,kg) = (r>>4)*64 +
// kg*16 + (r&15); frag reads and staging writes are lane-linear (conflict-free).
// bsel: element offset into Bt per 32768-row batch (for per-batch B), else 0.
// ---------------------------------------------------------------------------
__global__ __launch_bounds__(256) void gemm_hl(
    const unsigned short* __restrict__ Ah, const unsigned short* __restrict__ Al,
    const unsigned short* __restrict__ Bth, const unsigned short* __restrict__ Btl,
    const float* __restrict__ bias, float* __restrict__ OUT,
    int K, long bsel)
{
    __shared__ unsigned short Alds[2][128 * 32];
    __shared__ unsigned short Blds[2][128 * 32];
    const int t = threadIdx.x;
    const int row0 = blockIdx.x * 128;
    const int n0 = blockIdx.y * 128;
    const long boff = (long)(row0 >> 15) * bsel;
    const unsigned short* Bhp = Bth + boff;
    const unsigned short* Blp = Btl + boff;

    const int w = t >> 6, l = t & 63;
    const int wm = w >> 1, wn = w & 1;
    const int lr = l & 15, lk = l >> 4;

    f32x4 acc[4][4];
#pragma unroll
    for (int i = 0; i < 4; ++i)
#pragma unroll
        for (int j = 0; j < 4; ++j) {
            acc[i][j][0] = 0.f; acc[i][j][1] = 0.f;
            acc[i][j][2] = 0.f; acc[i][j][3] = 0.f;
        }

    for (int kk = 0; kk < K; kk += 32) {
        // global -> reg: wave w stages row-groups {w, w+4}; lane l handles
        // row g2*16+lr, k-group lk (16B chunk) of each of the 4 arrays.
        bf16x8 stg[8];
#pragma unroll
        for (int g2i = 0; g2i < 2; ++g2i) {
            const int g2 = w + g2i * 4;
            const size_t ar = (size_t)(row0 + g2 * 16 + lr) * K + kk + lk * 8;
            const size_t br = (size_t)(n0 + g2 * 16 + lr) * K + kk + lk * 8;
            stg[g2i * 4 + 0] = *(const bf16x8*)&Ah[ar];
            stg[g2i * 4 + 1] = *(const bf16x8*)&Al[ar];
            stg[g2i * 4 + 2] = *(const bf16x8*)&Bhp[br];
            stg[g2i * 4 + 3] = *(const bf16x8*)&Blp[br];
        }
        __syncthreads();   // previous tile's LDS reads complete
#pragma unroll
        for (int g2i = 0; g2i < 2; ++g2i) {
            const int g2 = w + g2i * 4;
            const int lc = (g2 * 64 + l) * 8;   // lane-linear chunk
            *(bf16x8*)&Alds[0][lc] = stg[g2i * 4 + 0];
            *(bf16x8*)&Alds[1][lc] = stg[g2i * 4 + 1];
            *(bf16x8*)&Blds[0][lc] = stg[g2i * 4 + 2];
            *(bf16x8*)&Blds[1][lc] = stg[g2i * 4 + 3];
        }
        __syncthreads();

        bf16x8 ah[4], al[4], bh[4], bl[4];
#pragma unroll
        for (int g = 0; g < 4; ++g) {
            const int ac = (((wm * 4 + g) * 4 + lk) * 16 + lr) * 8;
            ah[g] = *(const bf16x8*)&Alds[0][ac];
            al[g] = *(const bf16x8*)&Alds[1][ac];
            const int bc = (((wn * 4 + g) * 4 + lk) * 16 + lr) * 8;
            bh[g] = *(const bf16x8*)&Blds[0][bc];
            bl[g] = *(const bf16x8*)&Blds[1][bc];
        }
#pragma unroll
        for (int m = 0; m < 4; ++m)
#pragma unroll
            for (int n = 0; n < 4; ++n) {
                acc[m][n] = __builtin_amdgcn_mfma_f32_16x16x32_bf16(ah[m], bh[n], acc[m][n], 0, 0, 0);
                acc[m][n] = __builtin_amdgcn_mfma_f32_16x16x32_bf16(ah[m], bl[n], acc[m][n], 0, 0, 0);
                acc[m][n] = __builtin_amdgcn_mfma_f32_16x16x32_bf16(al[m], bh[n], acc[m][n], 0, 0, 0);
            }
    }

    // epilogue: C/D frag mapping col = lane&15, row = (lane>>4)*4 + reg
    float bv[4];
#pragma unroll
    for (int n = 0; n < 4; ++n) bv[n] = bias[n0 + wn * 64 + n * 16 + lr];
#pragma unroll
    for (int m = 0; m < 4; ++m)
#pragma unroll
        for (int n = 0; n < 4; ++n) {
            const int col = n0 + wn * 64 + n * 16 + lr;
#pragma unroll
            for (int r = 0; r < 4; ++r) {
                const int row = row0 + wm * 64 + m * 16 + lk * 4 + r;
                OUT[(size_t)row * 256 + col] = acc[m][n][r] + bv[n];
            }
        }
}

// ---------------------------------------------------------------------------
// K1b: logits = XM_head @ W_slice + b_slice, /temp[h], softmax over S=64.
// Writes SW as bf16 hi/lo pairs (SWh, SWl) [M][512].
// ---------------------------------------------------------------------------
__global__ __launch_bounds__(256) void k1b_slice_softmax(
    const float* __restrict__ XM, const float* __restrict__ Wsl,
    const float* __restrict__ bsl, const float* __restrict__ temp,
    unsigned short* __restrict__ SWh, unsigned short* __restrict__ SWl)
{
    __shared__ float XMs[32][68];  // [c][m]
    __shared__ float Ws[32][68];   // [c][s]
    __shared__ float Ls[64][68];   // logits tile [row][s]
    const int t  = threadIdx.x;
    const int r0 = blockIdx.x * 64;
    const int h  = blockIdx.y;

    {
        const int m = t >> 2, cq = (t & 3) * 8;
        float4 v0 = *(const float4*)&XM[(size_t)(r0 + m) * 256 + h * 32 + cq];
        float4 v1 = *(const float4*)&XM[(size_t)(r0 + m) * 256 + h * 32 + cq + 4];
        XMs[cq + 0][m] = v0.x; XMs[cq + 1][m] = v0.y; XMs[cq + 2][m] = v0.z; XMs[cq + 3][m] = v0.w;
        XMs[cq + 4][m] = v1.x; XMs[cq + 5][m] = v1.y; XMs[cq + 6][m] = v1.z; XMs[cq + 7][m] = v1.w;
        const int wk = t >> 3, wn = (t & 7) * 8;
        float4 u0 = *(const float4*)&Wsl[wk * 64 + wn];
        float4 u1 = *(const float4*)&Wsl[wk * 64 + wn + 4];
        *(float4*)&Ws[wk][wn]     = u0;
        *(float4*)&Ws[wk][wn + 4] = u1;
    }
    __syncthreads();

    const int tx = t & 15, ty = t >> 4;
    float acc[4][4];
#pragma unroll
    for (int i = 0; i < 4; ++i)
#pragma unroll
        for (int j = 0; j < 4; ++j) acc[i][j] = 0.f;
#pragma unroll
    for (int c = 0; c < 32; ++c) {
        float4 av = *(const float4*)&XMs[c][ty * 4];
        float4 bv = *(const float4*)&Ws[c][tx * 4];
        float a_[4] = {av.x, av.y, av.z, av.w};
        float b_[4] = {bv.x, bv.y, bv.z, bv.w};
#pragma unroll
        for (int i = 0; i < 4; ++i)
#pragma unroll
            for (int j = 0; j < 4; ++j)
                acc[i][j] = fmaf(a_[i], b_[j], acc[i][j]);
    }
    const float invt = 1.0f / temp[h];
#pragma unroll
    for (int i = 0; i < 4; ++i)
#pragma unroll
        for (int j = 0; j < 4; ++j)
            Ls[ty * 4 + i][tx * 4 + j] = (acc[i][j] + bsl[tx * 4 + j]) * invt;
    __syncthreads();

    const int row = t >> 2, j4 = t & 3;
    float v[16];
    float mx = -1e30f;
#pragma unroll
    for (int i = 0; i < 16; ++i) { v[i] = Ls[row][j4 * 16 + i]; mx = fmaxf(mx, v[i]); }
    mx = fmaxf(mx, __shfl_xor(mx, 1));
    mx = fmaxf(mx, __shfl_xor(mx, 2));
    float sum = 0.f;
#pragma unroll
    for (int i = 0; i < 16; ++i) { v[i] = expf(v[i] - mx); sum += v[i]; }
    sum += __shfl_xor(sum, 1);
    sum += __shfl_xor(sum, 2);
    const float inv = 1.0f / sum;
#pragma unroll
    for (int q = 0; q < 4; ++q) {
        us4 oh, ol;
#pragma unroll
        for (int j = 0; j < 4; ++j) {
            const float o = v[q * 4 + j] * inv;
            const unsigned short hh = f2bf(o);
            oh[j] = hh;
            ol[j] = f2bf(o - bf2f(hh));
        }
        const size_t idx = (size_t)(r0 + row) * 512 + h * 64 + j4 * 16 + q * 4;
        *(us4*)&SWh[idx] = oh;
        *(us4*)&SWl[idx] = ol;
    }
}

// ---------------------------------------------------------------------------
// K2: partial pooling per (bh, 1024-row chunk). SW read as bf16 hi/lo.
// ---------------------------------------------------------------------------
__global__ __launch_bounds__(256) void k2_pool(
    const float* __restrict__ FX,
    const unsigned short* __restrict__ SWh, const unsigned short* __restrict__ SWl,
    float* __restrict__ PART, float* __restrict__ PARTN)
{
    __shared__ float SWs[16][64];
    __shared__ float FXs[16][32];
    const int t = threadIdx.x;
    const int chunk = blockIdx.x;   // 0..31
    const int bh = blockIdx.y;      // 0..31
    const int b = bh >> 3, h = bh & 7;
    const int gbase = b * TS_N + chunk * 1024;
    const int c = t & 31, sb = (t >> 5) * 8;
    float acc[8];
#pragma unroll
    for (int j = 0; j < 8; ++j) acc[j] = 0.f;
    float accn = 0.f;

    for (int t0 = 0; t0 < 1024; t0 += 16) {
        {
            const int rr = t >> 4, s4 = (t & 15) * 4;
            const size_t idx = (size_t)(gbase + t0 + rr) * 512 + h * 64 + s4;
            const us4 vh = *(const us4*)&SWh[idx];
            const us4 vl = *(const us4*)&SWl[idx];
#pragma unroll
            for (int j = 0; j < 4; ++j)
                SWs[rr][s4 + j] = bf2f(vh[j]) + bf2f(vl[j]);
            if (t < 128) {
                const int r2 = t >> 3, c4 = (t & 7) * 4;
                *(float4*)&FXs[r2][c4] =
                    *(const float4*)&FX[(size_t)(gbase + t0 + r2) * 256 + h * 32 + c4];
            }
        }
        __syncthreads();
#pragma unroll
        for (int rr = 0; rr < 16; ++rr) {
            const float f = FXs[rr][c];
#pragma unroll
            for (int j = 0; j < 8; ++j)
                acc[j] = fmaf(f, SWs[rr][sb + j], acc[j]);
        }
        if (t < 64) {
#pragma unroll
            for (int rr = 0; rr < 16; ++rr) accn += SWs[rr][t];
        }
        __syncthreads();
    }
    const int pbase = (bh * 32 + chunk) * 2048;
#pragma unroll
    for (int j = 0; j < 8; ++j) PART[pbase + (sb + j) * 32 + c] = acc[j];
    if (t < 64) PARTN[(bh * 32 + chunk) * 64 + t] = accn;
}

// ---------------------------------------------------------------------------
// K2b: deterministic reduce of chunk partials.
// ---------------------------------------------------------------------------
__global__ __launch_bounds__(256) void k2b_reduce(
    const float* __restrict__ PART, const float* __restrict__ PARTN,
    float* __restrict__ ST, float* __restrict__ NORM)
{
    const int bh = blockIdx.x, t = threadIdx.x;
#pragma unroll
    for (int j = 0; j < 8; ++j) {
        const int e = j * 256 + t;
        float s = 0.f;
        for (int ch = 0; ch < 32; ++ch) s += PART[(bh * 32 + ch) * 2048 + e];
        ST[bh * 2048 + e] = s;
    }
    if (t < 64) {
        float s = 0.f;
        for (int ch = 0; ch < 32; ++ch) s += PARTN[(bh * 32 + ch) * 64 + t];
        NORM[bh * 64 + t] = s;
    }
}

// ---------------------------------------------------------------------------
// K3: tiny attention among 64 slice tokens per (b,h). 1 wave per block.
// ---------------------------------------------------------------------------
__global__ __launch_bounds__(64) void k3_attn(
    const float* __restrict__ ST, const float* __restrict__ NORM,
    const float* __restrict__ Wqkv, float* __restrict__ OST)
{
    __shared__ float Wq[32 * 96];
    __shared__ float Kl[64][32];
    __shared__ float Vl[64][32];
    __shared__ float Dl[64][68];
    const int bh = blockIdx.x;
    const int s  = threadIdx.x;

    for (int i = 0; i < 48; ++i) Wq[i * 64 + s] = Wqkv[i * 64 + s];
    float st[32];
    const float nrm = NORM[bh * 64 + s] + 1e-5f;
#pragma unroll
    for (int c = 0; c < 32; ++c) st[c] = ST[bh * 2048 + s * 32 + c] / nrm;
    __syncthreads();

    float q[32];
#pragma unroll
    for (int o4 = 0; o4 < 8; ++o4) {
        float ax = 0.f, ay = 0.f, az = 0.f, aw = 0.f;
#pragma unroll
        for (int c = 0; c < 32; ++c) {
            float4 w = *(const float4*)&Wq[c * 96 + o4 * 4];
            ax = fmaf(st[c], w.x, ax); ay = fmaf(st[c], w.y, ay);
            az = fmaf(st[c], w.z, az); aw = fmaf(st[c], w.w, aw);
        }
        q[o4 * 4 + 0] = ax; q[o4 * 4 + 1] = ay; q[o4 * 4 + 2] = az; q[o4 * 4 + 3] = aw;
    }
#pragma unroll
    for (int o4 = 0; o4 < 8; ++o4) {
        float ax = 0.f, ay = 0.f, az = 0.f, aw = 0.f;
#pragma unroll
        for (int c = 0; c < 32; ++c) {
            float4 w = *(const float4*)&Wq[c * 96 + 32 + o4 * 4];
            ax = fmaf(st[c], w.x, ax); ay = fmaf(st[c], w.y, ay);
            az = fmaf(st[c], w.z, az); aw = fmaf(st[c], w.w, aw);
        }
        float4 kv; kv.x = ax; kv.y = ay; kv.z = az; kv.w = aw;
        *(float4*)&Kl[s][o4 * 4] = kv;
    }
#pragma unroll
    for (int o4 = 0; o4 < 8; ++o4) {
        float ax = 0.f, ay = 0.f, az = 0.f, aw = 0.f;
#pragma unroll
        for (int c = 0; c < 32; ++c) {
            float4 w = *(const float4*)&Wq[c * 96 + 64 + o4 * 4];
            ax = fmaf(st[c], w.x, ax); ay = fmaf(st[c], w.y, ay);
            az = fmaf(st[c], w.z, az); aw = fmaf(st[c], w.w, aw);
        }
        float4 vv; vv.x = ax; vv.y = ay; vv.z = az; vv.w = aw;
        *(float4*)&Vl[s][o4 * 4] = vv;
    }
    __syncthreads();

    const float scale = 0.17677669529663687f;  // 32^-0.5
    float mx = -1e30f;
    for (int t2 = 0; t2 < 64; ++t2) {
        float d = 0.f;
#pragma unroll
        for (int c4 = 0; c4 < 8; ++c4) {
            float4 kv = *(const float4*)&Kl[t2][c4 * 4];
            d = fmaf(q[c4 * 4 + 0], kv.x, d); d = fmaf(q[c4 * 4 + 1], kv.y, d);
            d = fmaf(q[c4 * 4 + 2], kv.z, d); d = fmaf(q[c4 * 4 + 3], kv.w, d);
        }
        d *= scale;
        Dl[s][t2] = d;
        mx = fmaxf(mx, d);
    }
    float sum = 0.f;
    for (int t2 = 0; t2 < 64; ++t2) { float e = expf(Dl[s][t2] - mx); Dl[s][t2] = e; sum += e; }
    const float inv = 1.0f / sum;
    float out[32];
#pragma unroll
    for (int c = 0; c < 32; ++c) out[c] = 0.f;
    for (int t2 = 0; t2 < 64; ++t2) {
        const float p = Dl[s][t2] * inv;
#pragma unroll
        for (int c4 = 0; c4 < 8; ++c4) {
            float4 vv = *(const float4*)&Vl[t2][c4 * 4];
            out[c4 * 4 + 0] = fmaf(p, vv.x, out[c4 * 4 + 0]);
            out[c4 * 4 + 1] = fmaf(p, vv.y, out[c4 * 4 + 1]);
            out[c4 * 4 + 2] = fmaf(p, vv.z, out[c4 * 4 + 2]);
            out[c4 * 4 + 3] = fmaf(p, vv.w, out[c4 * 4 + 3]);
        }
    }
#pragma unroll
    for (int c4 = 0; c4 < 8; ++c4) {
        float4 ov;
        ov.x = out[c4 * 4 + 0]; ov.y = out[c4 * 4 + 1];
        ov.z = out[c4 * 4 + 2]; ov.w = out[c4 * 4 + 3];
        *(float4*)&OST[bh * 2048 + s * 32 + c4 * 4] = ov;
    }
}

// ---------------------------------------------------------------------------
// K3b: G[b, h*64+s, :] = OST[bh,s,:] @ Wout[h*32:(h+1)*32, :], written
// TRANSPOSED as bf16 hi/lo: Gt[b][n=256][k=512].
// ---------------------------------------------------------------------------
__global__ __launch_bounds__(256) void k3b_precomb(
    const float* __restrict__ OST, const float* __restrict__ Wout,
    unsigned short* __restrict__ Gth, unsigned short* __restrict__ Gtl)
{
    __shared__ float OSTs[64][36];   // [s][c], padded
    __shared__ float Wc[32][256];    // [c][o]
    const int bh = blockIdx.x;
    const int b = bh >> 3, h = bh & 7;
    const int t = threadIdx.x;

#pragma unroll
    for (int j = 0; j < 2; ++j) {
        const int e = (j * 256 + t) * 4;       // 0..2044, step 4
        float4 v = *(const float4*)&OST[bh * 2048 + e];
        const int s = e >> 5, c = e & 31;
        OSTs[s][c + 0] = v.x; OSTs[s][c + 1] = v.y;
        OSTs[s][c + 2] = v.z; OSTs[s][c + 3] = v.w;
    }
#pragma unroll
    for (int j = 0; j < 8; ++j) {
        const int e = (j * 256 + t) * 4;       // 0..8188
        const int c = e >> 8, o = e & 255;
        *(float4*)&Wc[c][o] = *(const float4*)&Wout[(h * 32 + c) * 256 + o];
    }
    __syncthreads();

    float wcol[32];
#pragma unroll
    for (int c = 0; c < 32; ++c) wcol[c] = Wc[c][t];

    for (int s = 0; s < 64; ++s) {
        float a = 0.f;
#pragma unroll
        for (int c = 0; c < 32; ++c) a = fmaf(OSTs[s][c], wcol[c], a);
        const unsigned short gh = f2bf(a);
        const size_t idx = ((size_t)(b * 256 + t)) * 512 + h * 64 + s;
        Gth[idx] = gh;
        Gtl[idx] = f2bf(a - bf2f(gh));
    }
}

extern "C" void kernel_launch(void* const* d_in, const int* in_sizes, int n_in,
                              void* d_out, int out_size, void* d_ws, size_t ws_size,
                              hipStream_t stream) {
    (void)in_sizes; (void)n_in; (void)out_size; (void)ws_size;
    const float* x    = (const float*)d_in[0];
    const float* Wfx  = (const float*)d_in[1];
    const float* bfx  = (const float*)d_in[2];
    const float* Wx   = (const float*)d_in[3];
    const float* bx   = (const float*)d_in[4];
    const float* Wsl  = (const float*)d_in[5];
    const float* bsl  = (const float*)d_in[6];
    const float* temp = (const float*)d_in[7];
    const float* Wqkv = (const float*)d_in[8];
    const float* Wout = (const float*)d_in[9];
    const float* bout = (const float*)d_in[10];
    float* out = (float*)d_out;
    char* w = (char*)d_ws;

    // ws layout (bytes):
    // [0, 128M):            XM f32  (131072*256*4 = 134,217,728)
    // [128M, 128M+256M):    SHARED: Xh|Xl (67MB+67MB) then SWh|SWl (128MB+128MB)
    //                       (SW written by k1b strictly after last X read in gemm)
    // then PART/PARTN/ST/NORM/OST/Gt/Wt
    float* XM = (float*)w;
    char* sh = w + 134217728;
    unsigned short* Xh  = (unsigned short*)sh;                    // 33,554,432 elems
    unsigned short* Xl  = Xh + 33554432;
    unsigned short* SWh = (unsigned short*)sh;                    // 67,108,864 elems
    unsigned short* SWl = SWh + 67108864;
    char* p = w + 134217728 + 268435456;
    float* PART  = (float*)p;            p += 8388608;    // 2,097,152 f
    float* PARTN = (float*)p;            p += 262144;     // 65,536 f
    float* ST    = (float*)p;            p += 262144;     // 65,536 f
    float* NORM  = (float*)p;            p += 8192;       // 2,048 f
    float* OST   = (float*)p;            p += 262144;     // 65,536 f
    unsigned short* Gth = (unsigned short*)p; p += 1048576;  // 524,288 us
    unsigned short* Gtl = (unsigned short*)p; p += 1048576;
    unsigned short* Wth = (unsigned short*)p; p += 262144;   // 131,072 us
    unsigned short* Wtl = (unsigned short*)p; p += 262144;
    float* FX = out;   // d_out doubles as FX scratch (read by k2, overwritten by k4)

    k0_split<<<2048, 256, 0, stream>>>(x, Xh, Xl, TS_M * 256 / 4);
    k0_wt<<<dim3(256, 2), 256, 0, stream>>>(Wfx, Wx, Wth, Wtl);
    gemm_hl<<<dim3(TS_M / 128, 2), 256, 0, stream>>>(Xh, Xl, Wth, Wtl, bfx, FX, 256, 0);
    gemm_hl<<<dim3(TS_M / 128, 2), 256, 0, stream>>>(Xh, Xl, Wth + 65536, Wtl + 65536, bx, XM, 256, 0);
    k1b_slice_softmax<<<dim3(TS_M / 64, 8), 256, 0, stream>>>(XM, Wsl, bsl, temp, SWh, SWl);
    k2_pool<<<dim3(32, 32), 256, 0, stream>>>(FX, SWh, SWl, PART, PARTN);
    k2b_reduce<<<32, 256, 0, stream>>>(PART, PARTN, ST, NORM);
    k3_attn<<<32, 64, 0, stream>>>(ST, NORM, Wqkv, OST);
    k3b_precomb<<<32, 256, 0, stream>>>(OST, Wout, Gth, Gtl);
    gemm_hl<<<dim3(TS_M / 128, 2), 256, 0, stream>>>(SWh, SWl, Gth, Gtl, bout, out, 512, 131072);
}

// Round 5
// 695.114 us; speedup vs baseline: 3.8008x; 1.2208x over previous
//
#include <hip/hip_runtime.h>
#include <math.h>

// Problem constants: B=4, N=32768, D=256, H=8, S=64, DH=32
#define TS_N 32768
#define TS_M 131072   // B*N

typedef short bf16x8 __attribute__((ext_vector_type(8)));
typedef float f32x4  __attribute__((ext_vector_type(4)));
typedef unsigned short us4 __attribute__((ext_vector_type(4)));
typedef unsigned short us8 __attribute__((ext_vector_type(8)));

static __device__ __forceinline__ unsigned short f2bf(float f) {
    unsigned u = __float_as_uint(f);
    u = u + 0x7FFF + ((u >> 16) & 1);   // RNE
    return (unsigned short)(u >> 16);
}
static __device__ __forceinline__ float bf2f(unsigned short b) {
    return __uint_as_float(((unsigned)b) << 16);
}

// ---------------------------------------------------------------------------
// K0: split x (f32) -> Xh, Xl (bf16 hi/lo), vectorized 4-wide
// ---------------------------------------------------------------------------
__global__ __launch_bounds__(256) void k0_split(
    const float* __restrict__ src, unsigned short* __restrict__ h,
    unsigned short* __restrict__ l, int n4)
{
    for (int i = blockIdx.x * 256 + threadIdx.x; i < n4; i += gridDim.x * 256) {
        float4 v = ((const float4*)src)[i];
        us4 vh, vl;
        float c[4] = {v.x, v.y, v.z, v.w};
#pragma unroll
        for (int j = 0; j < 4; ++j) {
            unsigned short hh = f2bf(c[j]);
            vh[j] = hh;
            vl[j] = f2bf(c[j] - bf2f(hh));
        }
        ((us4*)h)[i] = vh;
        ((us4*)l)[i] = vl;
    }
}

// ---------------------------------------------------------------------------
// K0w: convert + transpose Wfx, Wx -> Wt[w][n][k] bf16 hi/lo
// ---------------------------------------------------------------------------
__global__ __launch_bounds__(256) void k0_wt(
    const float* __restrict__ Wfx, const float* __restrict__ Wx,
    unsigned short* __restrict__ Wth, unsigned short* __restrict__ Wtl)
{
    const int n = blockIdx.x;       // 0..255 (output col of W = row of Wt)
    const int wsel = blockIdx.y;    // 0..1
    const int k = threadIdx.x;      // 0..255
    const float v = (wsel ? Wx : Wfx)[k * 256 + n];
    const unsigned short hh = f2bf(v);
    const int idx = (wsel * 256 + n) * 256 + k;
    Wth[idx] = hh;
    Wtl[idx] = f2bf(v - bf2f(hh));
}

// ---------------------------------------------------------------------------
// GEMM (split-bf16 MFMA): OUT[M][256] = (Ah+Al)[M][K] @ (Bh+Bl)^T[256][K] + bias
// BM=128, BN=128, BK=32, 256 thr = 4 waves, 64x64/wave, 3 MFMAs per frag.
// ---------------------------------------------------------------------------
__global__ __launch_bounds__(256) void gemm_hl(
    const unsigned short* __restrict__ Ah, const unsigned short* __restrict__ Al,
    const unsigned short* __restrict__ Bth, const unsigned short* __restrict__ Btl,
    const float* __restrict__ bias, float* __restrict__ OUT,
    int K, long bsel)
{
    __shared__ unsigned short Alds[2][128 * 32];
    __shared__ unsigned short Blds[2][128 * 32];
    const int t = threadIdx.x;
    const int row0 = blockIdx.x * 128;
    const int n0 = blockIdx.y * 128;
    const long boff = (long)(row0 >> 15) * bsel;
    const unsigned short* Bhp = Bth + boff;
    const unsigned short* Blp = Btl + boff;

    const int w = t >> 6, l = t & 63;
    const int wm = w >> 1, wn = w & 1;
    const int lr = l & 15, lk = l >> 4;

    f32x4 acc[4][4];
#pragma unroll
    for (int i = 0; i < 4; ++i)
#pragma unroll
        for (int j = 0; j < 4; ++j) {
            acc[i][j][0] = 0.f; acc[i][j][1] = 0.f;
            acc[i][j][2] = 0.f; acc[i][j][3] = 0.f;
        }

    for (int kk = 0; kk < K; kk += 32) {
        bf16x8 stg[8];
#pragma unroll
        for (int g2i = 0; g2i < 2; ++g2i) {
            const int g2 = w + g2i * 4;
            const size_t ar = (size_t)(row0 + g2 * 16 + lr) * K + kk + lk * 8;
            const size_t br = (size_t)(n0 + g2 * 16 + lr) * K + kk + lk * 8;
            stg[g2i * 4 + 0] = *(const bf16x8*)&Ah[ar];
            stg[g2i * 4 + 1] = *(const bf16x8*)&Al[ar];
            stg[g2i * 4 + 2] = *(const bf16x8*)&Bhp[br];
            stg[g2i * 4 + 3] = *(const bf16x8*)&Blp[br];
        }
        __syncthreads();
#pragma unroll
        for (int g2i = 0; g2i < 2; ++g2i) {
            const int g2 = w + g2i * 4;
            const int lc = (g2 * 64 + l) * 8;
            *(bf16x8*)&Alds[0][lc] = stg[g2i * 4 + 0];
            *(bf16x8*)&Alds[1][lc] = stg[g2i * 4 + 1];
            *(bf16x8*)&Blds[0][lc] = stg[g2i * 4 + 2];
            *(bf16x8*)&Blds[1][lc] = stg[g2i * 4 + 3];
        }
        __syncthreads();

        bf16x8 ah[4], al[4], bh[4], bl[4];
#pragma unroll
        for (int g = 0; g < 4; ++g) {
            const int ac = (((wm * 4 + g) * 4 + lk) * 16 + lr) * 8;
            ah[g] = *(const bf16x8*)&Alds[0][ac];
            al[g] = *(const bf16x8*)&Alds[1][ac];
            const int bc = (((wn * 4 + g) * 4 + lk) * 16 + lr) * 8;
            bh[g] = *(const bf16x8*)&Blds[0][bc];
            bl[g] = *(const bf16x8*)&Blds[1][bc];
        }
#pragma unroll
        for (int m = 0; m < 4; ++m)
#pragma unroll
            for (int n = 0; n < 4; ++n) {
                acc[m][n] = __builtin_amdgcn_mfma_f32_16x16x32_bf16(ah[m], bh[n], acc[m][n], 0, 0, 0);
                acc[m][n] = __builtin_amdgcn_mfma_f32_16x16x32_bf16(ah[m], bl[n], acc[m][n], 0, 0, 0);
                acc[m][n] = __builtin_amdgcn_mfma_f32_16x16x32_bf16(al[m], bh[n], acc[m][n], 0, 0, 0);
            }
    }

    float bv[4];
#pragma unroll
    for (int n = 0; n < 4; ++n) bv[n] = bias[n0 + wn * 64 + n * 16 + lr];
#pragma unroll
    for (int m = 0; m < 4; ++m)
#pragma unroll
        for (int n = 0; n < 4; ++n) {
            const int col = n0 + wn * 64 + n * 16 + lr;
#pragma unroll
            for (int r = 0; r < 4; ++r) {
                const int row = row0 + wm * 64 + m * 16 + lk * 4 + r;
                OUT[(size_t)row * 256 + col] = acc[m][n][r] + bv[n];
            }
        }
}

// ---------------------------------------------------------------------------
// K1b: logits = XM_head @ W_slice + b_slice, /temp[h], softmax over S=64.
// Writes SW as bf16 hi/lo pairs (SWh, SWl) [M][512].
// ---------------------------------------------------------------------------
__global__ __launch_bounds__(256) void k1b_slice_softmax(
    const float* __restrict__ XM, const float* __restrict__ Wsl,
    const float* __restrict__ bsl, const float* __restrict__ temp,
    unsigned short* __restrict__ SWh, unsigned short* __restrict__ SWl)
{
    __shared__ float XMs[32][68];  // [c][m]
    __shared__ float Ws[32][68];   // [c][s]
    __shared__ float Ls[64][68];   // logits tile [row][s]
    const int t  = threadIdx.x;
    const int r0 = blockIdx.x * 64;
    const int h  = blockIdx.y;

    {
        const int m = t >> 2, cq = (t & 3) * 8;
        float4 v0 = *(const float4*)&XM[(size_t)(r0 + m) * 256 + h * 32 + cq];
        float4 v1 = *(const float4*)&XM[(size_t)(r0 + m) * 256 + h * 32 + cq + 4];
        XMs[cq + 0][m] = v0.x; XMs[cq + 1][m] = v0.y; XMs[cq + 2][m] = v0.z; XMs[cq + 3][m] = v0.w;
        XMs[cq + 4][m] = v1.x; XMs[cq + 5][m] = v1.y; XMs[cq + 6][m] = v1.z; XMs[cq + 7][m] = v1.w;
        const int wk = t >> 3, wn = (t & 7) * 8;
        float4 u0 = *(const float4*)&Wsl[wk * 64 + wn];
        float4 u1 = *(const float4*)&Wsl[wk * 64 + wn + 4];
        *(float4*)&Ws[wk][wn]     = u0;
        *(float4*)&Ws[wk][wn + 4] = u1;
    }
    __syncthreads();

    const int tx = t & 15, ty = t >> 4;
    float acc[4][4];
#pragma unroll
    for (int i = 0; i < 4; ++i)
#pragma unroll
        for (int j = 0; j < 4; ++j) acc[i][j] = 0.f;
#pragma unroll
    for (int c = 0; c < 32; ++c) {
        float4 av = *(const float4*)&XMs[c][ty * 4];
        float4 bv = *(const float4*)&Ws[c][tx * 4];
        float a_[4] = {av.x, av.y, av.z, av.w};
        float b_[4] = {bv.x, bv.y, bv.z, bv.w};
#pragma unroll
        for (int i = 0; i < 4; ++i)
#pragma unroll
            for (int j = 0; j < 4; ++j)
                acc[i][j] = fmaf(a_[i], b_[j], acc[i][j]);
    }
    const float invt = 1.0f / temp[h];
#pragma unroll
    for (int i = 0; i < 4; ++i)
#pragma unroll
        for (int j = 0; j < 4; ++j)
            Ls[ty * 4 + i][tx * 4 + j] = (acc[i][j] + bsl[tx * 4 + j]) * invt;
    __syncthreads();

    const int row = t >> 2, j4 = t & 3;
    float v[16];
    float mx = -1e30f;
#pragma unroll
    for (int i = 0; i < 16; ++i) { v[i] = Ls[row][j4 * 16 + i]; mx = fmaxf(mx, v[i]); }
    mx = fmaxf(mx, __shfl_xor(mx, 1));
    mx = fmaxf(mx, __shfl_xor(mx, 2));
    float sum = 0.f;
#pragma unroll
    for (int i = 0; i < 16; ++i) { v[i] = expf(v[i] - mx); sum += v[i]; }
    sum += __shfl_xor(sum, 1);
    sum += __shfl_xor(sum, 2);
    const float inv = 1.0f / sum;
#pragma unroll
    for (int q = 0; q < 4; ++q) {
        us4 oh, ol;
#pragma unroll
        for (int j = 0; j < 4; ++j) {
            const float o = v[q * 4 + j] * inv;
            const unsigned short hh = f2bf(o);
            oh[j] = hh;
            ol[j] = f2bf(o - bf2f(hh));
        }
        const size_t idx = (size_t)(r0 + row) * 512 + h * 64 + j4 * 16 + q * 4;
        *(us4*)&SWh[idx] = oh;
        *(us4*)&SWl[idx] = ol;
    }
}

// ---------------------------------------------------------------------------
// K2 v2: partial pooling. Grid (64 chunks x 32 bh), 512 rows/chunk.
// 64-row slabs, reg-prefetch + double-buffered LDS, ONE barrier per slab.
// PART[bh][chunk][s][c], PARTN[bh][chunk][s].
// ---------------------------------------------------------------------------
__global__ __launch_bounds__(256) void k2_pool(
    const float* __restrict__ FX,
    const unsigned short* __restrict__ SWh, const unsigned short* __restrict__ SWl,
    float* __restrict__ PART, float* __restrict__ PARTN)
{
    __shared__ float SWs[2][64][68];
    __shared__ float FXs[2][64][36];
    const int t = threadIdx.x;
    const int chunk = blockIdx.x;   // 0..63
    const int bh = blockIdx.y;      // 0..31
    const int b = bh >> 3, h = bh & 7;
    const int gbase = b * TS_N + chunk * 512;

    const int rs = t >> 2;          // staging row 0..63
    const int ch0 = t & 3;          // staging chunk: ch0 and ch0+4

    us8 swh[2], swl[2];
    float4 fxr[2];

    // prefetch slab 0
    {
        const size_t swbase = (size_t)(gbase + rs) * 512 + h * 64;
        swh[0] = *(const us8*)&SWh[swbase + ch0 * 8];
        swh[1] = *(const us8*)&SWh[swbase + (ch0 + 4) * 8];
        swl[0] = *(const us8*)&SWl[swbase + ch0 * 8];
        swl[1] = *(const us8*)&SWl[swbase + (ch0 + 4) * 8];
        const size_t fxbase = (size_t)(gbase + rs) * 256 + h * 32;
        fxr[0] = *(const float4*)&FX[fxbase + ch0 * 4];
        fxr[1] = *(const float4*)&FX[fxbase + (ch0 + 4) * 4];
    }

    const int c = t & 31, sb = (t >> 5) * 8;
    float acc[8];
#pragma unroll
    for (int j = 0; j < 8; ++j) acc[j] = 0.f;
    float accn = 0.f;
    int buf = 0;

    for (int s = 0; s < 8; ++s) {
        // regs -> LDS (combine hi+lo)
#pragma unroll
        for (int q = 0; q < 2; ++q) {
            const int cq = (ch0 + q * 4) * 8;
#pragma unroll
            for (int j = 0; j < 8; ++j)
                SWs[buf][rs][cq + j] = bf2f(swh[q][j]) + bf2f(swl[q][j]);
            *(float4*)&FXs[buf][rs][(ch0 + q * 4) * 4] = fxr[q];
        }
        __syncthreads();
        // prefetch next slab
        if (s < 7) {
            const int g2 = gbase + (s + 1) * 64 + rs;
            const size_t swbase = (size_t)g2 * 512 + h * 64;
            swh[0] = *(const us8*)&SWh[swbase + ch0 * 8];
            swh[1] = *(const us8*)&SWh[swbase + (ch0 + 4) * 8];
            swl[0] = *(const us8*)&SWl[swbase + ch0 * 8];
            swl[1] = *(const us8*)&SWl[swbase + (ch0 + 4) * 8];
            const size_t fxbase = (size_t)g2 * 256 + h * 32;
            fxr[0] = *(const float4*)&FX[fxbase + ch0 * 4];
            fxr[1] = *(const float4*)&FX[fxbase + (ch0 + 4) * 4];
        }
        // compute from LDS[buf]
#pragma unroll 8
        for (int rr = 0; rr < 64; ++rr) {
            const float f = FXs[buf][rr][c];
            float4 s0 = *(const float4*)&SWs[buf][rr][sb];
            float4 s1 = *(const float4*)&SWs[buf][rr][sb + 4];
            acc[0] = fmaf(f, s0.x, acc[0]); acc[1] = fmaf(f, s0.y, acc[1]);
            acc[2] = fmaf(f, s0.z, acc[2]); acc[3] = fmaf(f, s0.w, acc[3]);
            acc[4] = fmaf(f, s1.x, acc[4]); acc[5] = fmaf(f, s1.y, acc[5]);
            acc[6] = fmaf(f, s1.z, acc[6]); acc[7] = fmaf(f, s1.w, acc[7]);
        }
        if (t < 64) {
#pragma unroll 8
            for (int rr = 0; rr < 64; ++rr) accn += SWs[buf][rr][t];
        }
        buf ^= 1;
    }

    const int pbase = (bh * 64 + chunk) * 2048;
#pragma unroll
    for (int j = 0; j < 8; ++j) PART[pbase + (sb + j) * 32 + c] = acc[j];
    if (t < 64) PARTN[(bh * 64 + chunk) * 64 + t] = accn;
}

// ---------------------------------------------------------------------------
// K2b: deterministic reduce of 64 chunk partials. Grid (8 groups x 32 bh).
// ---------------------------------------------------------------------------
__global__ __launch_bounds__(256) void k2b_reduce(
    const float* __restrict__ PART, const float* __restrict__ PARTN,
    float* __restrict__ ST, float* __restrict__ NORM)
{
    const int g = blockIdx.x, bh = blockIdx.y, t = threadIdx.x;
    const int e = g * 256 + t;
    float s = 0.f;
    for (int ch = 0; ch < 64; ++ch) s += PART[(size_t)(bh * 64 + ch) * 2048 + e];
    ST[bh * 2048 + e] = s;
    if (g == 0 && t < 64) {
        float sn = 0.f;
        for (int ch = 0; ch < 64; ++ch) sn += PARTN[(bh * 64 + ch) * 64 + t];
        NORM[bh * 64 + t] = sn;
    }
}

// ---------------------------------------------------------------------------
// K3: tiny attention among 64 slice tokens per (b,h). 1 wave per block.
// ---------------------------------------------------------------------------
__global__ __launch_bounds__(64) void k3_attn(
    const float* __restrict__ ST, const float* __restrict__ NORM,
    const float* __restrict__ Wqkv, float* __restrict__ OST)
{
    __shared__ float Wq[32 * 96];
    __shared__ float Kl[64][32];
    __shared__ float Vl[64][32];
    __shared__ float Dl[64][68];
    const int bh = blockIdx.x;
    const int s  = threadIdx.x;

    for (int i = 0; i < 48; ++i) Wq[i * 64 + s] = Wqkv[i * 64 + s];
    float st[32];
    const float nrm = NORM[bh * 64 + s] + 1e-5f;
#pragma unroll
    for (int c = 0; c < 32; ++c) st[c] = ST[bh * 2048 + s * 32 + c] / nrm;
    __syncthreads();

    float q[32];
#pragma unroll
    for (int o4 = 0; o4 < 8; ++o4) {
        float ax = 0.f, ay = 0.f, az = 0.f, aw = 0.f;
#pragma unroll
        for (int c = 0; c < 32; ++c) {
            float4 w = *(const float4*)&Wq[c * 96 + o4 * 4];
            ax = fmaf(st[c], w.x, ax); ay = fmaf(st[c], w.y, ay);
            az = fmaf(st[c], w.z, az); aw = fmaf(st[c], w.w, aw);
        }
        q[o4 * 4 + 0] = ax; q[o4 * 4 + 1] = ay; q[o4 * 4 + 2] = az; q[o4 * 4 + 3] = aw;
    }
#pragma unroll
    for (int o4 = 0; o4 < 8; ++o4) {
        float ax = 0.f, ay = 0.f, az = 0.f, aw = 0.f;
#pragma unroll
        for (int c = 0; c < 32; ++c) {
            float4 w = *(const float4*)&Wq[c * 96 + 32 + o4 * 4];
            ax = fmaf(st[c], w.x, ax); ay = fmaf(st[c], w.y, ay);
            az = fmaf(st[c], w.z, az); aw = fmaf(st[c], w.w, aw);
        }
        float4 kv; kv.x = ax; kv.y = ay; kv.z = az; kv.w = aw;
        *(float4*)&Kl[s][o4 * 4] = kv;
    }
#pragma unroll
    for (int o4 = 0; o4 < 8; ++o4) {
        float ax = 0.f, ay = 0.f, az = 0.f, aw = 0.f;
#pragma unroll
        for (int c = 0; c < 32; ++c) {
            float4 w = *(const float4*)&Wq[c * 96 + 64 + o4 * 4];
            ax = fmaf(st[c], w.x, ax); ay = fmaf(st[c], w.y, ay);
            az = fmaf(st[c], w.z, az); aw = fmaf(st[c], w.w, aw);
        }
        float4 vv; vv.x = ax; vv.y = ay; vv.z = az; vv.w = aw;
        *(float4*)&Vl[s][o4 * 4] = vv;
    }
    __syncthreads();

    const float scale = 0.17677669529663687f;  // 32^-0.5
    float mx = -1e30f;
    for (int t2 = 0; t2 < 64; ++t2) {
        float d = 0.f;
#pragma unroll
        for (int c4 = 0; c4 < 8; ++c4) {
            float4 kv = *(const float4*)&Kl[t2][c4 * 4];
            d = fmaf(q[c4 * 4 + 0], kv.x, d); d = fmaf(q[c4 * 4 + 1], kv.y, d);
            d = fmaf(q[c4 * 4 + 2], kv.z, d); d = fmaf(q[c4 * 4 + 3], kv.w, d);
        }
        d *= scale;
        Dl[s][t2] = d;
        mx = fmaxf(mx, d);
    }
    float sum = 0.f;
    for (int t2 = 0; t2 < 64; ++t2) { float e = expf(Dl[s][t2] - mx); Dl[s][t2] = e; sum += e; }
    const float inv = 1.0f / sum;
    float out[32];
#pragma unroll
    for (int c = 0; c < 32; ++c) out[c] = 0.f;
    for (int t2 = 0; t2 < 64; ++t2) {
        const float p = Dl[s][t2] * inv;
#pragma unroll
        for (int c4 = 0; c4 < 8; ++c4) {
            float4 vv = *(const float4*)&Vl[t2][c4 * 4];
            out[c4 * 4 + 0] = fmaf(p, vv.x, out[c4 * 4 + 0]);
            out[c4 * 4 + 1] = fmaf(p, vv.y, out[c4 * 4 + 1]);
            out[c4 * 4 + 2] = fmaf(p, vv.z, out[c4 * 4 + 2]);
            out[c4 * 4 + 3] = fmaf(p, vv.w, out[c4 * 4 + 3]);
        }
    }
#pragma unroll
    for (int c4 = 0; c4 < 8; ++c4) {
        float4 ov;
        ov.x = out[c4 * 4 + 0]; ov.y = out[c4 * 4 + 1];
        ov.z = out[c4 * 4 + 2]; ov.w = out[c4 * 4 + 3];
        *(float4*)&OST[bh * 2048 + s * 32 + c4 * 4] = ov;
    }
}

// ---------------------------------------------------------------------------
// K3b: G[b, h*64+s, :] = OST[bh,s,:] @ Wout[h*32:(h+1)*32, :], written
// TRANSPOSED as bf16 hi/lo: Gt[b][n=256][k=512].
// ---------------------------------------------------------------------------
__global__ __launch_bounds__(256) void k3b_precomb(
    const float* __restrict__ OST, const float* __restrict__ Wout,
    unsigned short* __restrict__ Gth, unsigned short* __restrict__ Gtl)
{
    __shared__ float OSTs[64][36];   // [s][c], padded
    __shared__ float Wc[32][256];    // [c][o]
    const int bh = blockIdx.x;
    const int b = bh >> 3, h = bh & 7;
    const int t = threadIdx.x;

#pragma unroll
    for (int j = 0; j < 2; ++j) {
        const int e = (j * 256 + t) * 4;       // 0..2044, step 4
        float4 v = *(const float4*)&OST[bh * 2048 + e];
        const int s = e >> 5, c = e & 31;
        OSTs[s][c + 0] = v.x; OSTs[s][c + 1] = v.y;
        OSTs[s][c + 2] = v.z; OSTs[s][c + 3] = v.w;
    }
#pragma unroll
    for (int j = 0; j < 8; ++j) {
        const int e = (j * 256 + t) * 4;       // 0..8188
        const int c = e >> 8, o = e & 255;
        *(float4*)&Wc[c][o] = *(const float4*)&Wout[(h * 32 + c) * 256 + o];
    }
    __syncthreads();

    float wcol[32];
#pragma unroll
    for (int c = 0; c < 32; ++c) wcol[c] = Wc[c][t];

    for (int s = 0; s < 64; ++s) {
        float a = 0.f;
#pragma unroll
        for (int c = 0; c < 32; ++c) a = fmaf(OSTs[s][c], wcol[c], a);
        const unsigned short gh = f2bf(a);
        const size_t idx = ((size_t)(b * 256 + t)) * 512 + h * 64 + s;
        Gth[idx] = gh;
        Gtl[idx] = f2bf(a - bf2f(gh));
    }
}

extern "C" void kernel_launch(void* const* d_in, const int* in_sizes, int n_in,
                              void* d_out, int out_size, void* d_ws, size_t ws_size,
                              hipStream_t stream) {
    (void)in_sizes; (void)n_in; (void)out_size; (void)ws_size;
    const float* x    = (const float*)d_in[0];
    const float* Wfx  = (const float*)d_in[1];
    const float* bfx  = (const float*)d_in[2];
    const float* Wx   = (const float*)d_in[3];
    const float* bx   = (const float*)d_in[4];
    const float* Wsl  = (const float*)d_in[5];
    const float* bsl  = (const float*)d_in[6];
    const float* temp = (const float*)d_in[7];
    const float* Wqkv = (const float*)d_in[8];
    const float* Wout = (const float*)d_in[9];
    const float* bout = (const float*)d_in[10];
    float* out = (float*)d_out;
    char* w = (char*)d_ws;

    // ws layout (bytes):
    // [0, 128M):         XM f32 (dead after k1b) -> reused for PART/PARTN by k2
    // [128M, 384M):      Xh|Xl (67+67MB) then SWh|SWl (128+128MB)
    // [384M+, ...):      ST/NORM/OST/Gt/Wt
    float* XM = (float*)w;
    char* sh = w + 134217728;
    unsigned short* Xh  = (unsigned short*)sh;                    // 33,554,432 elems
    unsigned short* Xl  = Xh + 33554432;
    unsigned short* SWh = (unsigned short*)sh;                    // 67,108,864 elems
    unsigned short* SWl = SWh + 67108864;
    char* p = w + 134217728 + 268435456;
    p += 8388608;   // (old PART slot, unused)
    p += 262144;    // (old PARTN slot, unused)
    float* ST    = (float*)p;            p += 262144;     // 65,536 f
    float* NORM  = (float*)p;            p += 8192;       // 2,048 f
    float* OST   = (float*)p;            p += 262144;     // 65,536 f
    unsigned short* Gth = (unsigned short*)p; p += 1048576;  // 524,288 us
    unsigned short* Gtl = (unsigned short*)p; p += 1048576;
    unsigned short* Wth = (unsigned short*)p; p += 262144;   // 131,072 us
    unsigned short* Wtl = (unsigned short*)p; p += 262144;
    // PART/PARTN live in the dead XM region (XM consumed by k1b before k2)
    float* PART  = XM;                   // 32*64*2048 = 4,194,304 f (16.8MB)
    float* PARTN = XM + 4194304;         // 32*64*64  = 131,072 f
    float* FX = out;   // d_out doubles as FX scratch (read by k2, overwritten by final gemm)

    k0_split<<<2048, 256, 0, stream>>>(x, Xh, Xl, TS_M * 256 / 4);
    k0_wt<<<dim3(256, 2), 256, 0, stream>>>(Wfx, Wx, Wth, Wtl);
    gemm_hl<<<dim3(TS_M / 128, 2), 256, 0, stream>>>(Xh, Xl, Wth, Wtl, bfx, FX, 256, 0);
    gemm_hl<<<dim3(TS_M / 128, 2), 256, 0, stream>>>(Xh, Xl, Wth + 65536, Wtl + 65536, bx, XM, 256, 0);
    k1b_slice_softmax<<<dim3(TS_M / 64, 8), 256, 0, stream>>>(XM, Wsl, bsl, temp, SWh, SWl);
    k2_pool<<<dim3(64, 32), 256, 0, stream>>>(FX, SWh, SWl, PART, PARTN);
    k2b_reduce<<<dim3(8, 32), 256, 0, stream>>>(PART, PARTN, ST, NORM);
    k3_attn<<<32, 64, 0, stream>>>(ST, NORM, Wqkv, OST);
    k3b_precomb<<<32, 256, 0, stream>>>(OST, Wout, Gth, Gtl);
    gemm_hl<<<dim3(TS_M / 128, 2), 256, 0, stream>>>(SWh, SWl, Gth, Gtl, bout, out, 512, 131072);
}

// Round 6
// 668.730 us; speedup vs baseline: 3.9507x; 1.0395x over previous
//
#include <hip/hip_runtime.h>
#include <math.h>

// Problem constants: B=4, N=32768, D=256, H=8, S=64, DH=32
#define TS_N 32768
#define TS_M 131072   // B*N

typedef short bf16x8 __attribute__((ext_vector_type(8)));
typedef float f32x4  __attribute__((ext_vector_type(4)));
typedef unsigned short us4 __attribute__((ext_vector_type(4)));
typedef unsigned short us8 __attribute__((ext_vector_type(8)));

static __device__ __forceinline__ unsigned short f2bf(float f) {
    unsigned u = __float_as_uint(f);
    u = u + 0x7FFF + ((u >> 16) & 1);   // RNE
    return (unsigned short)(u >> 16);
}
static __device__ __forceinline__ float bf2f(unsigned short b) {
    return __uint_as_float(((unsigned)b) << 16);
}

// ---------------------------------------------------------------------------
// K0: split x (f32) -> Xh, Xl (bf16 hi/lo), vectorized 4-wide
// ---------------------------------------------------------------------------
__global__ __launch_bounds__(256) void k0_split(
    const float* __restrict__ src, unsigned short* __restrict__ h,
    unsigned short* __restrict__ l, int n4)
{
    for (int i = blockIdx.x * 256 + threadIdx.x; i < n4; i += gridDim.x * 256) {
        float4 v = ((const float4*)src)[i];
        us4 vh, vl;
        float c[4] = {v.x, v.y, v.z, v.w};
#pragma unroll
        for (int j = 0; j < 4; ++j) {
            unsigned short hh = f2bf(c[j]);
            vh[j] = hh;
            vl[j] = f2bf(c[j] - bf2f(hh));
        }
        ((us4*)h)[i] = vh;
        ((us4*)l)[i] = vl;
    }
}

// ---------------------------------------------------------------------------
// K0w: convert + transpose Wfx, Wx -> Wt[w][n][k] bf16 hi/lo
// ---------------------------------------------------------------------------
__global__ __launch_bounds__(256) void k0_wt(
    const float* __restrict__ Wfx, const float* __restrict__ Wx,
    unsigned short* __restrict__ Wth, unsigned short* __restrict__ Wtl)
{
    const int n = blockIdx.x;       // 0..255 (output col of W = row of Wt)
    const int wsel = blockIdx.y;    // 0..1
    const int k = threadIdx.x;      // 0..255
    const float v = (wsel ? Wx : Wfx)[k * 256 + n];
    const unsigned short hh = f2bf(v);
    const int idx = (wsel * 256 + n) * 256 + k;
    Wth[idx] = hh;
    Wtl[idx] = f2bf(v - bf2f(hh));
}

// ---------------------------------------------------------------------------
// Shared pipelined split-bf16 MFMA GEMM body.
// OUT[row0:+128, n0:+128] = (Ah+Al)[M][K] @ (Bth+Btl)^T[128][K] + bias[n0:]
// Bth/Btl pre-offset to the 128-row B panel. BM=128,BN=128,BK=32, 4 waves.
// Register-prefetch pipeline: next tile's global loads issue before the MFMA
// phase of the current tile (latency hidden under 48 MFMAs + frag ds_reads).
// ---------------------------------------------------------------------------
template<int K>
static __device__ __forceinline__ void gemm_body(
    const unsigned short* __restrict__ Ah, const unsigned short* __restrict__ Al,
    const unsigned short* __restrict__ Bth, const unsigned short* __restrict__ Btl,
    const float* __restrict__ bias, float* __restrict__ OUT,
    int row0, int n0)
{
    __shared__ unsigned short Alds[2][128 * 32];
    __shared__ unsigned short Blds[2][128 * 32];
    const int t = threadIdx.x;
    const int w = t >> 6, l = t & 63;
    const int wm = w >> 1, wn = w & 1;
    const int lr = l & 15, lk = l >> 4;

    f32x4 acc[4][4];
#pragma unroll
    for (int i = 0; i < 4; ++i)
#pragma unroll
        for (int j = 0; j < 4; ++j) {
            acc[i][j][0] = 0.f; acc[i][j][1] = 0.f;
            acc[i][j][2] = 0.f; acc[i][j][3] = 0.f;
        }

    bf16x8 sA[2][2], sB[2][2];
    // prologue: load tile 0
#pragma unroll
    for (int g2i = 0; g2i < 2; ++g2i) {
        const int g2 = w + g2i * 4;
        const size_t ar = (size_t)(row0 + g2 * 16 + lr) * K + lk * 8;
        const size_t br = (size_t)(g2 * 16 + lr) * K + lk * 8;
        sA[g2i][0] = *(const bf16x8*)&Ah[ar];
        sA[g2i][1] = *(const bf16x8*)&Al[ar];
        sB[g2i][0] = *(const bf16x8*)&Bth[br];
        sB[g2i][1] = *(const bf16x8*)&Btl[br];
    }

    const int NSTEP = K / 32;
    for (int step = 0; step < NSTEP; ++step) {
        __syncthreads();   // prior tile's LDS reads complete
#pragma unroll
        for (int g2i = 0; g2i < 2; ++g2i) {
            const int lc = ((w + g2i * 4) * 64 + l) * 8;
            *(bf16x8*)&Alds[0][lc] = sA[g2i][0];
            *(bf16x8*)&Alds[1][lc] = sA[g2i][1];
            *(bf16x8*)&Blds[0][lc] = sB[g2i][0];
            *(bf16x8*)&Blds[1][lc] = sB[g2i][1];
        }
        __syncthreads();
        // prefetch next tile (lands under the MFMA phase below)
        if (step < NSTEP - 1) {
            const int kk = (step + 1) * 32;
#pragma unroll
            for (int g2i = 0; g2i < 2; ++g2i) {
                const int g2 = w + g2i * 4;
                const size_t ar = (size_t)(row0 + g2 * 16 + lr) * K + kk + lk * 8;
                const size_t br = (size_t)(g2 * 16 + lr) * K + kk + lk * 8;
                sA[g2i][0] = *(const bf16x8*)&Ah[ar];
                sA[g2i][1] = *(const bf16x8*)&Al[ar];
                sB[g2i][0] = *(const bf16x8*)&Bth[br];
                sB[g2i][1] = *(const bf16x8*)&Btl[br];
            }
        }

        bf16x8 ah[4], al[4], bh[4], bl[4];
#pragma unroll
        for (int g = 0; g < 4; ++g) {
            const int ac = (((wm * 4 + g) * 4 + lk) * 16 + lr) * 8;
            ah[g] = *(const bf16x8*)&Alds[0][ac];
            al[g] = *(const bf16x8*)&Alds[1][ac];
            const int bc = (((wn * 4 + g) * 4 + lk) * 16 + lr) * 8;
            bh[g] = *(const bf16x8*)&Blds[0][bc];
            bl[g] = *(const bf16x8*)&Blds[1][bc];
        }
#pragma unroll
        for (int m = 0; m < 4; ++m)
#pragma unroll
            for (int n = 0; n < 4; ++n) {
                acc[m][n] = __builtin_amdgcn_mfma_f32_16x16x32_bf16(ah[m], bh[n], acc[m][n], 0, 0, 0);
                acc[m][n] = __builtin_amdgcn_mfma_f32_16x16x32_bf16(ah[m], bl[n], acc[m][n], 0, 0, 0);
                acc[m][n] = __builtin_amdgcn_mfma_f32_16x16x32_bf16(al[m], bh[n], acc[m][n], 0, 0, 0);
            }
    }

    float bv[4];
#pragma unroll
    for (int n = 0; n < 4; ++n) bv[n] = bias[n0 + wn * 64 + n * 16 + lr];
#pragma unroll
    for (int m = 0; m < 4; ++m)
#pragma unroll
        for (int n = 0; n < 4; ++n) {
            const int col = n0 + wn * 64 + n * 16 + lr;
#pragma unroll
            for (int r = 0; r < 4; ++r) {
                const int row = row0 + wm * 64 + m * 16 + lk * 4 + r;
                OUT[(size_t)row * 256 + col] = acc[m][n][r] + bv[n];
            }
        }
}

// ---------------------------------------------------------------------------
// K1: fused FX+XM GEMM. 4096 blocks, XCD-swizzled: L -> xcd=L&7, ii=L>>3,
// rowblock = xcd*128 + ii>>2, nsel = ii&3 (0,1: W_fx cols 0/128 -> FX;
// 2,3: W_x -> XM). The 4 nsel-blocks of a rowblock are consecutive in-XCD
// slots -> concurrent on one XCD -> A tile L2-shared.
// ---------------------------------------------------------------------------
__global__ __launch_bounds__(256) void k1_gemm(
    const unsigned short* __restrict__ Ah, const unsigned short* __restrict__ Al,
    const unsigned short* __restrict__ Wth, const unsigned short* __restrict__ Wtl,
    const float* __restrict__ bfx, const float* __restrict__ bx,
    float* __restrict__ FX, float* __restrict__ XM)
{
    const int L = blockIdx.x;
    const int xcd = L & 7, ii = L >> 3;
    const int rb = xcd * 128 + (ii >> 2), nsel = ii & 3;
    const int row0 = rb * 128;
    const int n0 = (nsel & 1) * 128;
    const unsigned short* Bth = Wth + (nsel >> 1) * 65536 + n0 * 256;
    const unsigned short* Btl = Wtl + (nsel >> 1) * 65536 + n0 * 256;
    const float* bias = (nsel >> 1) ? bx : bfx;
    float* OUT = (nsel >> 1) ? XM : FX;
    gemm_body<256>(Ah, Al, Bth, Btl, bias, OUT, row0, n0);
}

// ---------------------------------------------------------------------------
// K4: out = SW[131072x512] @ Gt_b^T + bout. 2048 blocks, XCD-swizzled pairs.
// ---------------------------------------------------------------------------
__global__ __launch_bounds__(256) void k4_gemm(
    const unsigned short* __restrict__ SWh, const unsigned short* __restrict__ SWl,
    const unsigned short* __restrict__ Gth, const unsigned short* __restrict__ Gtl,
    const float* __restrict__ bout, float* __restrict__ out)
{
    const int L = blockIdx.x;
    const int xcd = L & 7, ii = L >> 3;
    const int rb = xcd * 128 + (ii >> 1), nsel = ii & 1;
    const int row0 = rb * 128;
    const int n0 = nsel * 128;
    const int b = row0 >> 15;
    const unsigned short* Bth = Gth + ((size_t)b * 256 + n0) * 512;
    const unsigned short* Btl = Gtl + ((size_t)b * 256 + n0) * 512;
    gemm_body<512>(SWh, SWl, Bth, Btl, bout, out, row0, n0);
}

// ---------------------------------------------------------------------------
// K1b: logits = XM_head @ W_slice + b_slice, /temp[h], softmax over S=64.
// Writes SW as bf16 hi/lo pairs (SWh, SWl) [M][512].
// ---------------------------------------------------------------------------
__global__ __launch_bounds__(256) void k1b_slice_softmax(
    const float* __restrict__ XM, const float* __restrict__ Wsl,
    const float* __restrict__ bsl, const float* __restrict__ temp,
    unsigned short* __restrict__ SWh, unsigned short* __restrict__ SWl)
{
    __shared__ float XMs[32][68];  // [c][m]
    __shared__ float Ws[32][68];   // [c][s]
    __shared__ float Ls[64][68];   // logits tile [row][s]
    const int t  = threadIdx.x;
    const int r0 = blockIdx.x * 64;
    const int h  = blockIdx.y;

    {
        const int m = t >> 2, cq = (t & 3) * 8;
        float4 v0 = *(const float4*)&XM[(size_t)(r0 + m) * 256 + h * 32 + cq];
        float4 v1 = *(const float4*)&XM[(size_t)(r0 + m) * 256 + h * 32 + cq + 4];
        XMs[cq + 0][m] = v0.x; XMs[cq + 1][m] = v0.y; XMs[cq + 2][m] = v0.z; XMs[cq + 3][m] = v0.w;
        XMs[cq + 4][m] = v1.x; XMs[cq + 5][m] = v1.y; XMs[cq + 6][m] = v1.z; XMs[cq + 7][m] = v1.w;
        const int wk = t >> 3, wn = (t & 7) * 8;
        float4 u0 = *(const float4*)&Wsl[wk * 64 + wn];
        float4 u1 = *(const float4*)&Wsl[wk * 64 + wn + 4];
        *(float4*)&Ws[wk][wn]     = u0;
        *(float4*)&Ws[wk][wn + 4] = u1;
    }
    __syncthreads();

    const int tx = t & 15, ty = t >> 4;
    float acc[4][4];
#pragma unroll
    for (int i = 0; i < 4; ++i)
#pragma unroll
        for (int j = 0; j < 4; ++j) acc[i][j] = 0.f;
#pragma unroll
    for (int c = 0; c < 32; ++c) {
        float4 av = *(const float4*)&XMs[c][ty * 4];
        float4 bv = *(const float4*)&Ws[c][tx * 4];
        float a_[4] = {av.x, av.y, av.z, av.w};
        float b_[4] = {bv.x, bv.y, bv.z, bv.w};
#pragma unroll
        for (int i = 0; i < 4; ++i)
#pragma unroll
            for (int j = 0; j < 4; ++j)
                acc[i][j] = fmaf(a_[i], b_[j], acc[i][j]);
    }
    const float invt = 1.0f / temp[h];
#pragma unroll
    for (int i = 0; i < 4; ++i)
#pragma unroll
        for (int j = 0; j < 4; ++j)
            Ls[ty * 4 + i][tx * 4 + j] = (acc[i][j] + bsl[tx * 4 + j]) * invt;
    __syncthreads();

    const int row = t >> 2, j4 = t & 3;
    float v[16];
    float mx = -1e30f;
#pragma unroll
    for (int i = 0; i < 16; ++i) { v[i] = Ls[row][j4 * 16 + i]; mx = fmaxf(mx, v[i]); }
    mx = fmaxf(mx, __shfl_xor(mx, 1));
    mx = fmaxf(mx, __shfl_xor(mx, 2));
    float sum = 0.f;
#pragma unroll
    for (int i = 0; i < 16; ++i) { v[i] = expf(v[i] - mx); sum += v[i]; }
    sum += __shfl_xor(sum, 1);
    sum += __shfl_xor(sum, 2);
    const float inv = 1.0f / sum;
#pragma unroll
    for (int q = 0; q < 4; ++q) {
        us4 oh, ol;
#pragma unroll
        for (int j = 0; j < 4; ++j) {
            const float o = v[q * 4 + j] * inv;
            const unsigned short hh = f2bf(o);
            oh[j] = hh;
            ol[j] = f2bf(o - bf2f(hh));
        }
        const size_t idx = (size_t)(r0 + row) * 512 + h * 64 + j4 * 16 + q * 4;
        *(us4*)&SWh[idx] = oh;
        *(us4*)&SWl[idx] = ol;
    }
}

// ---------------------------------------------------------------------------
// K2 v2: partial pooling. Grid (64 chunks x 32 bh), 512 rows/chunk.
// 64-row slabs, reg-prefetch + double-buffered LDS, ONE barrier per slab.
// ---------------------------------------------------------------------------
__global__ __launch_bounds__(256) void k2_pool(
    const float* __restrict__ FX,
    const unsigned short* __restrict__ SWh, const unsigned short* __restrict__ SWl,
    float* __restrict__ PART, float* __restrict__ PARTN)
{
    __shared__ float SWs[2][64][68];
    __shared__ float FXs[2][64][36];
    const int t = threadIdx.x;
    const int chunk = blockIdx.x;   // 0..63
    const int bh = blockIdx.y;      // 0..31
    const int b = bh >> 3, h = bh & 7;
    const int gbase = b * TS_N + chunk * 512;

    const int rs = t >> 2;          // staging row 0..63
    const int ch0 = t & 3;          // staging chunk: ch0 and ch0+4

    us8 swh[2], swl[2];
    float4 fxr[2];

    {
        const size_t swbase = (size_t)(gbase + rs) * 512 + h * 64;
        swh[0] = *(const us8*)&SWh[swbase + ch0 * 8];
        swh[1] = *(const us8*)&SWh[swbase + (ch0 + 4) * 8];
        swl[0] = *(const us8*)&SWl[swbase + ch0 * 8];
        swl[1] = *(const us8*)&SWl[swbase + (ch0 + 4) * 8];
        const size_t fxbase = (size_t)(gbase + rs) * 256 + h * 32;
        fxr[0] = *(const float4*)&FX[fxbase + ch0 * 4];
        fxr[1] = *(const float4*)&FX[fxbase + (ch0 + 4) * 4];
    }

    const int c = t & 31, sb = (t >> 5) * 8;
    float acc[8];
#pragma unroll
    for (int j = 0; j < 8; ++j) acc[j] = 0.f;
    float accn = 0.f;
    int buf = 0;

    for (int s = 0; s < 8; ++s) {
#pragma unroll
        for (int q = 0; q < 2; ++q) {
            const int cq = (ch0 + q * 4) * 8;
#pragma unroll
            for (int j = 0; j < 8; ++j)
                SWs[buf][rs][cq + j] = bf2f(swh[q][j]) + bf2f(swl[q][j]);
            *(float4*)&FXs[buf][rs][(ch0 + q * 4) * 4] = fxr[q];
        }
        __syncthreads();
        if (s < 7) {
            const int g2 = gbase + (s + 1) * 64 + rs;
            const size_t swbase = (size_t)g2 * 512 + h * 64;
            swh[0] = *(const us8*)&SWh[swbase + ch0 * 8];
            swh[1] = *(const us8*)&SWh[swbase + (ch0 + 4) * 8];
            swl[0] = *(const us8*)&SWl[swbase + ch0 * 8];
            swl[1] = *(const us8*)&SWl[swbase + (ch0 + 4) * 8];
            const size_t fxbase = (size_t)g2 * 256 + h * 32;
            fxr[0] = *(const float4*)&FX[fxbase + ch0 * 4];
            fxr[1] = *(const float4*)&FX[fxbase + (ch0 + 4) * 4];
        }
#pragma unroll 8
        for (int rr = 0; rr < 64; ++rr) {
            const float f = FXs[buf][rr][c];
            float4 s0 = *(const float4*)&SWs[buf][rr][sb];
            float4 s1 = *(const float4*)&SWs[buf][rr][sb + 4];
            acc[0] = fmaf(f, s0.x, acc[0]); acc[1] = fmaf(f, s0.y, acc[1]);
            acc[2] = fmaf(f, s0.z, acc[2]); acc[3] = fmaf(f, s0.w, acc[3]);
            acc[4] = fmaf(f, s1.x, acc[4]); acc[5] = fmaf(f, s1.y, acc[5]);
            acc[6] = fmaf(f, s1.z, acc[6]); acc[7] = fmaf(f, s1.w, acc[7]);
        }
        if (t < 64) {
#pragma unroll 8
            for (int rr = 0; rr < 64; ++rr) accn += SWs[buf][rr][t];
        }
        buf ^= 1;
    }

    const int pbase = (bh * 64 + chunk) * 2048;
#pragma unroll
    for (int j = 0; j < 8; ++j) PART[pbase + (sb + j) * 32 + c] = acc[j];
    if (t < 64) PARTN[(bh * 64 + chunk) * 64 + t] = accn;
}

// ---------------------------------------------------------------------------
// K2b: deterministic reduce of 64 chunk partials. Grid (8 groups x 32 bh).
// ---------------------------------------------------------------------------
__global__ __launch_bounds__(256) void k2b_reduce(
    const float* __restrict__ PART, const float* __restrict__ PARTN,
    float* __restrict__ ST, float* __restrict__ NORM)
{
    const int g = blockIdx.x, bh = blockIdx.y, t = threadIdx.x;
    const int e = g * 256 + t;
    float s = 0.f;
    for (int ch = 0; ch < 64; ++ch) s += PART[(size_t)(bh * 64 + ch) * 2048 + e];
    ST[bh * 2048 + e] = s;
    if (g == 0 && t < 64) {
        float sn = 0.f;
        for (int ch = 0; ch < 64; ++ch) sn += PARTN[(bh * 64 + ch) * 64 + t];
        NORM[bh * 64 + t] = sn;
    }
}

// ---------------------------------------------------------------------------
// K3: tiny attention among 64 slice tokens per (b,h). 1 wave per block.
// ---------------------------------------------------------------------------
__global__ __launch_bounds__(64) void k3_attn(
    const float* __restrict__ ST, const float* __restrict__ NORM,
    const float* __restrict__ Wqkv, float* __restrict__ OST)
{
    __shared__ float Wq[32 * 96];
    __shared__ float Kl[64][32];
    __shared__ float Vl[64][32];
    __shared__ float Dl[64][68];
    const int bh = blockIdx.x;
    const int s  = threadIdx.x;

    for (int i = 0; i < 48; ++i) Wq[i * 64 + s] = Wqkv[i * 64 + s];
    float st[32];
    const float nrm = NORM[bh * 64 + s] + 1e-5f;
#pragma unroll
    for (int c = 0; c < 32; ++c) st[c] = ST[bh * 2048 + s * 32 + c] / nrm;
    __syncthreads();

    float q[32];
#pragma unroll
    for (int o4 = 0; o4 < 8; ++o4) {
        float ax = 0.f, ay = 0.f, az = 0.f, aw = 0.f;
#pragma unroll
        for (int c = 0; c < 32; ++c) {
            float4 w = *(const float4*)&Wq[c * 96 + o4 * 4];
            ax = fmaf(st[c], w.x, ax); ay = fmaf(st[c], w.y, ay);
            az = fmaf(st[c], w.z, az); aw = fmaf(st[c], w.w, aw);
        }
        q[o4 * 4 + 0] = ax; q[o4 * 4 + 1] = ay; q[o4 * 4 + 2] = az; q[o4 * 4 + 3] = aw;
    }
#pragma unroll
    for (int o4 = 0; o4 < 8; ++o4) {
        float ax = 0.f, ay = 0.f, az = 0.f, aw = 0.f;
#pragma unroll
        for (int c = 0; c < 32; ++c) {
            float4 w = *(const float4*)&Wq[c * 96 + 32 + o4 * 4];
            ax = fmaf(st[c], w.x, ax); ay = fmaf(st[c], w.y, ay);
            az = fmaf(st[c], w.z, az); aw = fmaf(st[c], w.w, aw);
        }
        float4 kv; kv.x = ax; kv.y = ay; kv.z = az; kv.w = aw;
        *(float4*)&Kl[s][o4 * 4] = kv;
    }
#pragma unroll
    for (int o4 = 0; o4 < 8; ++o4) {
        float ax = 0.f, ay = 0.f, az = 0.f, aw = 0.f;
#pragma unroll
        for (int c = 0; c < 32; ++c) {
            float4 w = *(const float4*)&Wq[c * 96 + 64 + o4 * 4];
            ax = fmaf(st[c], w.x, ax); ay = fmaf(st[c], w.y, ay);
            az = fmaf(st[c], w.z, az); aw = fmaf(st[c], w.w, aw);
        }
        float4 vv; vv.x = ax; vv.y = ay; vv.z = az; vv.w = aw;
        *(float4*)&Vl[s][o4 * 4] = vv;
    }
    __syncthreads();

    const float scale = 0.17677669529663687f;  // 32^-0.5
    float mx = -1e30f;
    for (int t2 = 0; t2 < 64; ++t2) {
        float d = 0.f;
#pragma unroll
        for (int c4 = 0; c4 < 8; ++c4) {
            float4 kv = *(const float4*)&Kl[t2][c4 * 4];
            d = fmaf(q[c4 * 4 + 0], kv.x, d); d = fmaf(q[c4 * 4 + 1], kv.y, d);
            d = fmaf(q[c4 * 4 + 2], kv.z, d); d = fmaf(q[c4 * 4 + 3], kv.w, d);
        }
        d *= scale;
        Dl[s][t2] = d;
        mx = fmaxf(mx, d);
    }
    float sum = 0.f;
    for (int t2 = 0; t2 < 64; ++t2) { float e = expf(Dl[s][t2] - mx); Dl[s][t2] = e; sum += e; }
    const float inv = 1.0f / sum;
    float out[32];
#pragma unroll
    for (int c = 0; c < 32; ++c) out[c] = 0.f;
    for (int t2 = 0; t2 < 64; ++t2) {
        const float p = Dl[s][t2] * inv;
#pragma unroll
        for (int c4 = 0; c4 < 8; ++c4) {
            float4 vv = *(const float4*)&Vl[t2][c4 * 4];
            out[c4 * 4 + 0] = fmaf(p, vv.x, out[c4 * 4 + 0]);
            out[c4 * 4 + 1] = fmaf(p, vv.y, out[c4 * 4 + 1]);
            out[c4 * 4 + 2] = fmaf(p, vv.z, out[c4 * 4 + 2]);
            out[c4 * 4 + 3] = fmaf(p, vv.w, out[c4 * 4 + 3]);
        }
    }
#pragma unroll
    for (int c4 = 0; c4 < 8; ++c4) {
        float4 ov;
        ov.x = out[c4 * 4 + 0]; ov.y = out[c4 * 4 + 1];
        ov.z = out[c4 * 4 + 2]; ov.w = out[c4 * 4 + 3];
        *(float4*)&OST[bh * 2048 + s * 32 + c4 * 4] = ov;
    }
}

// ---------------------------------------------------------------------------
// K3b: G[b, h*64+s, :] = OST[bh,s,:] @ Wout[h*32:(h+1)*32, :], written
// TRANSPOSED as bf16 hi/lo: Gt[b][n=256][k=512].
// ---------------------------------------------------------------------------
__global__ __launch_bounds__(256) void k3b_precomb(
    const float* __restrict__ OST, const float* __restrict__ Wout,
    unsigned short* __restrict__ Gth, unsigned short* __restrict__ Gtl)
{
    __shared__ float OSTs[64][36];   // [s][c], padded
    __shared__ float Wc[32][256];    // [c][o]
    const int bh = blockIdx.x;
    const int b = bh >> 3, h = bh & 7;
    const int t = threadIdx.x;

#pragma unroll
    for (int j = 0; j < 2; ++j) {
        const int e = (j * 256 + t) * 4;       // 0..2044, step 4
        float4 v = *(const float4*)&OST[bh * 2048 + e];
        const int s = e >> 5, c = e & 31;
        OSTs[s][c + 0] = v.x; OSTs[s][c + 1] = v.y;
        OSTs[s][c + 2] = v.z; OSTs[s][c + 3] = v.w;
    }
#pragma unroll
    for (int j = 0; j < 8; ++j) {
        const int e = (j * 256 + t) * 4;       // 0..8188
        const int c = e >> 8, o = e & 255;
        *(float4*)&Wc[c][o] = *(const float4*)&Wout[(h * 32 + c) * 256 + o];
    }
    __syncthreads();

    float wcol[32];
#pragma unroll
    for (int c = 0; c < 32; ++c) wcol[c] = Wc[c][t];

    for (int s = 0; s < 64; ++s) {
        float a = 0.f;
#pragma unroll
        for (int c = 0; c < 32; ++c) a = fmaf(OSTs[s][c], wcol[c], a);
        const unsigned short gh = f2bf(a);
        const size_t idx = ((size_t)(b * 256 + t)) * 512 + h * 64 + s;
        Gth[idx] = gh;
        Gtl[idx] = f2bf(a - bf2f(gh));
    }
}

extern "C" void kernel_launch(void* const* d_in, const int* in_sizes, int n_in,
                              void* d_out, int out_size, void* d_ws, size_t ws_size,
                              hipStream_t stream) {
    (void)in_sizes; (void)n_in; (void)out_size; (void)ws_size;
    const float* x    = (const float*)d_in[0];
    const float* Wfx  = (const float*)d_in[1];
    const float* bfx  = (const float*)d_in[2];
    const float* Wx   = (const float*)d_in[3];
    const float* bx   = (const float*)d_in[4];
    const float* Wsl  = (const float*)d_in[5];
    const float* bsl  = (const float*)d_in[6];
    const float* temp = (const float*)d_in[7];
    const float* Wqkv = (const float*)d_in[8];
    const float* Wout = (const float*)d_in[9];
    const float* bout = (const float*)d_in[10];
    float* out = (float*)d_out;
    char* w = (char*)d_ws;

    // ws layout (bytes):
    // [0, 128M):         XM f32 (dead after k1b) -> reused for PART/PARTN by k2
    // [128M, 384M):      Xh|Xl (67+67MB) then SWh|SWl (128+128MB)
    // [384M+, ...):      ST/NORM/OST/Gt/Wt
    float* XM = (float*)w;
    char* sh = w + 134217728;
    unsigned short* Xh  = (unsigned short*)sh;                    // 33,554,432 elems
    unsigned short* Xl  = Xh + 33554432;
    unsigned short* SWh = (unsigned short*)sh;                    // 67,108,864 elems
    unsigned short* SWl = SWh + 67108864;
    char* p = w + 134217728 + 268435456;
    p += 8388608;   // (reserved)
    p += 262144;    // (reserved)
    float* ST    = (float*)p;            p += 262144;     // 65,536 f
    float* NORM  = (float*)p;            p += 8192;       // 2,048 f
    float* OST   = (float*)p;            p += 262144;     // 65,536 f
    unsigned short* Gth = (unsigned short*)p; p += 1048576;  // 524,288 us
    unsigned short* Gtl = (unsigned short*)p; p += 1048576;
    unsigned short* Wth = (unsigned short*)p; p += 262144;   // 131,072 us
    unsigned short* Wtl = (unsigned short*)p; p += 262144;
    // PART/PARTN live in the dead XM region (XM consumed by k1b before k2)
    float* PART  = XM;                   // 32*64*2048 = 4,194,304 f
    float* PARTN = XM + 4194304;         // 32*64*64  = 131,072 f
    float* FX = out;   // d_out doubles as FX scratch (read by k2, overwritten by k4)

    k0_split<<<2048, 256, 0, stream>>>(x, Xh, Xl, TS_M * 256 / 4);
    k0_wt<<<dim3(256, 2), 256, 0, stream>>>(Wfx, Wx, Wth, Wtl);
    k1_gemm<<<4096, 256, 0, stream>>>(Xh, Xl, Wth, Wtl, bfx, bx, FX, XM);
    k1b_slice_softmax<<<dim3(TS_M / 64, 8), 256, 0, stream>>>(XM, Wsl, bsl, temp, SWh, SWl);
    k2_pool<<<dim3(64, 32), 256, 0, stream>>>(FX, SWh, SWl, PART, PARTN);
    k2b_reduce<<<dim3(8, 32), 256, 0, stream>>>(PART, PARTN, ST, NORM);
    k3_attn<<<32, 64, 0, stream>>>(ST, NORM, Wqkv, OST);
    k3b_precomb<<<32, 256, 0, stream>>>(OST, Wout, Gth, Gtl);
    k4_gemm<<<2048, 256, 0, stream>>>(SWh, SWl, Gth, Gtl, bout, out);
}